// Round 4
// baseline (3878.904 us; speedup 1.0000x reference)
//
#include <hip/hip_runtime.h>
#include <hip/hip_bf16.h>

#define NB 64      // batch
#define NS 40      // src len
#define NT 39      // tgt steps (T-1)
#define NE 256     // emb
#define NU 1024    // hidden
#define G3 3072    // 3*U
#define NVO 8192

typedef __attribute__((ext_vector_type(8))) short short8_t;   // 8 x bf16 frag
typedef __attribute__((ext_vector_type(4))) float float4_t;   // 4 x f32 acc

// plane offsets (ushort counts)
#define PO_S  3145728   // step weights: 64 blk * 96 * 64 * 8
#define PO_GX 786432    // gx weights: 192 * 8 * 64 * 8
#define PO_FC 8388608   // fc weights: 512 * 32 * 64 * 8

// ---------------------------------------------------------------------------
__device__ __forceinline__ unsigned short f2bf(float x) {
    union { float f; unsigned u; } v; v.f = x;
    unsigned r = v.u + 0x7fffu + ((v.u >> 16) & 1u);
    return (unsigned short)(r >> 16);
}
__device__ __forceinline__ float bf2f(unsigned short h) {
    union { float f; unsigned u; } v; v.u = ((unsigned)h) << 16; return v.f;
}
__device__ __forceinline__ float sigmoidf_(float x) { return 1.0f / (1.0f + expf(-x)); }

// ---------------------------------------------------------------------------
// Agent-scope (cross-XCD coherent) access helpers, 32/64-bit ONLY.
// These compile to global_load/store ... sc1: they bypass the per-XCD L2 and
// hit the memory-side LLC (the coherence point). Because mutable data never
// lives in L2, NO __threadfence is needed anywhere, so the read-only working
// set (weights, gx, enc_out) stays hot in L2 across phases — the round-2
// device fence invalidated it every phase (975 MB refetch/dispatch, 2.1 ms).
// ---------------------------------------------------------------------------
__device__ __forceinline__ short8_t ld_coh_b128(const unsigned short* p) {
    const unsigned long long* q = (const unsigned long long*)p;
    unsigned long long a = __hip_atomic_load((unsigned long long*)q,
                                             __ATOMIC_RELAXED, __HIP_MEMORY_SCOPE_AGENT);
    unsigned long long b = __hip_atomic_load((unsigned long long*)(q + 1),
                                             __ATOMIC_RELAXED, __HIP_MEMORY_SCOPE_AGENT);
    union { unsigned long long u[2]; short8_t v; } r;
    r.u[0] = a; r.u[1] = b; return r.v;
}
__device__ __forceinline__ float ld_coh_f32(const float* p) {
    return __hip_atomic_load((float*)p, __ATOMIC_RELAXED, __HIP_MEMORY_SCOPE_AGENT);
}
__device__ __forceinline__ unsigned ld_coh_u32(const unsigned* p) {
    return __hip_atomic_load((unsigned*)p, __ATOMIC_RELAXED, __HIP_MEMORY_SCOPE_AGENT);
}
__device__ __forceinline__ void st_coh_f32(float* p, float v) {
    __hip_atomic_store(p, v, __ATOMIC_RELAXED, __HIP_MEMORY_SCOPE_AGENT);
}
__device__ __forceinline__ void st_coh_u32(unsigned* p, unsigned v) {
    __hip_atomic_store(p, v, __ATOMIC_RELAXED, __HIP_MEMORY_SCOPE_AGENT);
}

// ---------------------------------------------------------------------------
// Software grid barrier, fence-free. __syncthreads() drains vmcnt (compiler
// emits s_waitcnt vmcnt(0) before s_barrier), so every wave's sc1 stores are
// at the coherence point before thread 0 arrives. Monotonic counter, zeroed
// by a captured hipMemsetAsync each replay. Spin is BOUNDED: a residual bug
// shows up as a wrong answer (absmax signal) instead of a dead container.
// ---------------------------------------------------------------------------
__device__ __forceinline__ void gsync(unsigned* bar, unsigned goal)
{
    __syncthreads();
    if (threadIdx.x == 0) {
        __hip_atomic_fetch_add(bar, 1u, __ATOMIC_RELAXED, __HIP_MEMORY_SCOPE_AGENT);
        int spin = 0;
        while (__hip_atomic_load(bar, __ATOMIC_RELAXED, __HIP_MEMORY_SCOPE_AGENT) < goal
               && spin < 8192) {
            __builtin_amdgcn_s_sleep(1);
            ++spin;
        }
        asm volatile("" ::: "memory");   // compiler-only ordering, no ISA cache op
    }
    __syncthreads();
}

// ---------------------------------------------------------------------------
// Generic packer: K x N fp32 -> MFMA B-frag order hi/lo. grid (N/16, K/32).
// ---------------------------------------------------------------------------
__global__ __launch_bounds__(64) void k_pack_b(const float* __restrict__ W, int N,
                                               unsigned short* __restrict__ Bp, int planeOff)
{
    int nt = blockIdx.x, s = blockIdx.y;
    int l = threadIdx.x;
    int n = nt * 16 + (l & 15);
    int k0 = s * 32 + (l >> 4) * 8;
    size_t ob = (((size_t)nt * gridDim.y + s) * 64 + l) * 8;
#pragma unroll
    for (int jj = 0; jj < 8; ++jj) {
        float x = W[(size_t)(k0 + jj) * N + n];
        unsigned short h = f2bf(x);
        Bp[ob + jj] = h;
        Bp[planeOff + ob + jj] = f2bf(x - bf2f(h));
    }
}

// Step-weight packer: block j of the step kernel owns cols {g*1024 + 16j..+16}.
__global__ __launch_bounds__(64) void k_pack_step(const float* __restrict__ W,
                                                  unsigned short* __restrict__ Bp)
{
    int j = blockIdx.x;
    int q = blockIdx.y;            // g*32 + s
    int g = q >> 5, s = q & 31;
    int l = threadIdx.x;
    int n = g * NU + j * 16 + (l & 15);
    int k0 = s * 32 + (l >> 4) * 8;
    size_t ob = (((size_t)j * 96 + q) * 64 + l) * 8;
#pragma unroll
    for (int jj = 0; jj < 8; ++jj) {
        float x = W[(size_t)(k0 + jj) * G3 + n];
        unsigned short h = f2bf(x);
        Bp[ob + jj] = h;
        Bp[PO_S + ob + jj] = f2bf(x - bf2f(h));
    }
}

// Gather embeddings -> bf16 plane. grid (rows), block 256 (= NE).
__global__ __launch_bounds__(256) void k_gather(const int* __restrict__ idx,
                                                int cols_total, int cols_used,
                                                const float* __restrict__ emb,
                                                unsigned short* __restrict__ Ax)
{
    int row = blockIdx.x;
    int b = row / cols_used, c = row - b * cols_used;
    int tok = idx[b * cols_total + c];
    int k = threadIdx.x;
    Ax[(size_t)row * NE + k] = f2bf(emb[(size_t)tok * NE + k]);
}

// GX GEMM: out[row][col] = Ax[row][:256] @ W + bias. grid (M/64, 48), block 256.
__global__ __launch_bounds__(256) void k_gx_mfma(const unsigned short* __restrict__ Ax,
                                                 const unsigned short* __restrict__ Bp,
                                                 const float* __restrict__ bias,
                                                 float* __restrict__ out)
{
    int tx = threadIdx.x;
    int w = tx >> 6, l = tx & 63;
    int lq = l >> 4, lr = l & 15;
    int row0 = blockIdx.x * 64 + w * 16;
    int cb = blockIdx.y;                       // 48 n-blocks of 64
    float4_t acc[4] = {{0,0,0,0},{0,0,0,0},{0,0,0,0},{0,0,0,0}};
    const unsigned short* Ab = Ax + (size_t)(row0 + lr) * NE + lq * 8;
#pragma unroll
    for (int s = 0; s < 8; ++s) {
        short8_t ah = *(const short8_t*)(Ab + s * 32);
#pragma unroll
        for (int nf = 0; nf < 4; ++nf) {
            const unsigned short* bp = Bp + ((((size_t)cb * 4 + nf) * 8 + s) * 64 + l) * 8;
            short8_t bh = *(const short8_t*)bp;
            short8_t bl = *(const short8_t*)(bp + PO_GX);
            acc[nf] = __builtin_amdgcn_mfma_f32_16x16x32_bf16(ah, bh, acc[nf], 0, 0, 0);
            acc[nf] = __builtin_amdgcn_mfma_f32_16x16x32_bf16(ah, bl, acc[nf], 0, 0, 0);
        }
    }
#pragma unroll
    for (int nf = 0; nf < 4; ++nf) {
        int col = cb * 64 + nf * 16 + lr;
        float bi = bias[col];
#pragma unroll
        for (int r = 0; r < 4; ++r) {
            int gr = row0 + lq * 4 + r;
            out[(size_t)gr * G3 + col] = acc[nf][r] + bi;
        }
    }
}

// ---------------------------------------------------------------------------
// Shared-memory overlay for the persistent scan kernels.
// ---------------------------------------------------------------------------
union SMem {
    float red[4][4][3][256];                 // 48 KB  [kw][mw][g][16x16]
    struct { float h[NU]; float sc[64]; } at; // attention phase
};

// Attention phase body (1024 threads, one block per batch row b).
// COH_H: hsrc was sc1-written earlier in this kernel (decoder hdec).
// COH_CTX: ctx is re-read by a later phase of this kernel -> sc1 writes.
// eb (enc_out) reads are ALWAYS plain-cached: in the decoder it is read-only
// (L2-hot); in the encoder-final attention it is the first plain touch of
// that buffer in the dispatch, so no stale L2 line can exist.
template<bool COH_H, bool COH_CTX>
__device__ __forceinline__ void attn_phase(int b, int tx,
    const float* __restrict__ hsrc, int hstride,
    const float* __restrict__ enc_out,
    unsigned short* __restrict__ ctx_hi, unsigned short* __restrict__ ctx_lo,
    float* h_sh, float* sc_sh)
{
    int wave = tx >> 6, lane = tx & 63;
    h_sh[tx] = COH_H ? ld_coh_f32(hsrc + (size_t)b * hstride + tx)
                     : hsrc[(size_t)b * hstride + tx];
    __syncthreads();
    const float* eb = enc_out + (size_t)b * NS * NU;
    for (int s = wave; s < NS; s += 16) {
        const float* es = eb + (size_t)s * NU;
        float p = 0.f;
#pragma unroll
        for (int q = 0; q < NU / 64; ++q) p += h_sh[lane + q * 64] * es[lane + q * 64];
#pragma unroll
        for (int off = 32; off > 0; off >>= 1) p += __shfl_down(p, off);
        if (lane == 0) sc_sh[s] = p;
    }
    __syncthreads();
    if (wave == 0) {
        float v = (lane < NS) ? sc_sh[lane] : -3.0e38f;
        float m = v;
#pragma unroll
        for (int off = 32; off > 0; off >>= 1) m = fmaxf(m, __shfl_down(m, off));
        m = __shfl(m, 0);
        float e = (lane < NS) ? expf(v - m) : 0.f;
        float ss = e;
#pragma unroll
        for (int off = 32; off > 0; off >>= 1) ss += __shfl_down(ss, off);
        ss = __shfl(ss, 0);
        if (lane < NS) sc_sh[lane] = e / ss;
    }
    __syncthreads();
    {
        float c = 0.f;
#pragma unroll 8
        for (int s = 0; s < NS; ++s) c += sc_sh[s] * eb[(size_t)s * NU + tx];
        unsigned short h = f2bf(c);
        unsigned short lo = f2bf(c - bf2f(h));
        // pack (tx, tx+1) into one u32 store: 32-bit coherent ops only.
        unsigned vh = h, vl = lo;
        unsigned nh = __shfl_down(vh, 1);
        unsigned nl = __shfl_down(vl, 1);
        if (!(tx & 1)) {
            unsigned* ph = (unsigned*)(ctx_hi + (size_t)b * NU + tx);
            unsigned* pl = (unsigned*)(ctx_lo + (size_t)b * NU + tx);
            unsigned wh = vh | (nh << 16), wl = vl | (nl << 16);
            if (COH_CTX) { st_coh_u32(ph, wh); st_coh_u32(pl, wl); }
            else         { *ph = wh;           *pl = wl; }
        }
    }
}

// ---------------------------------------------------------------------------
// Persistent encoder scan: all 40 steps + initial decoder ctx in ONE plain
// kernel launch (64 blocks x 1024 thr, one block per CU => co-resident).
// Mutable h planes: sc1 (32/64-bit). Weights/gx: plain (L2-hot all scan).
// ---------------------------------------------------------------------------
__global__ __launch_bounds__(1024) void k_scan_enc(
    unsigned short* __restrict__ h_hi0, unsigned short* __restrict__ h_lo0,
    unsigned short* __restrict__ h_hi1, unsigned short* __restrict__ h_lo1,
    const unsigned short* __restrict__ Bp,
    const float* __restrict__ GX, const float* __restrict__ b1,
    float* __restrict__ enc_out,
    unsigned short* __restrict__ ctx_hi, unsigned short* __restrict__ ctx_lo,
    unsigned* bar)
{
    __shared__ SMem sm;
    int tx = threadIdx.x;
    int j = blockIdx.x;
    int w = tx >> 6, l = tx & 63;
    int lq = l >> 4, lr = l & 15;
    int mw = w & 3, kw = w >> 2;
    const unsigned short* Bb = Bp + (size_t)j * 96 * 512 + l * 8;
    unsigned ph = 0;

#pragma unroll 1
    for (int t = 0; t < NS; ++t) {
        const unsigned short* Ah = (t & 1) ? h_hi1 : h_hi0;
        const unsigned short* Al = (t & 1) ? h_lo1 : h_lo0;
        unsigned short* Oh = (t & 1) ? h_hi0 : h_hi1;
        unsigned short* Ol = (t & 1) ? h_lo0 : h_lo1;

        float4_t acc[3] = {{0,0,0,0},{0,0,0,0},{0,0,0,0}};
        const unsigned short* Ab  = Ah + (size_t)(mw * 16 + lr) * NU + kw * 256 + lq * 8;
        const unsigned short* Alb = Al + (size_t)(mw * 16 + lr) * NU + kw * 256 + lq * 8;
#pragma unroll
        for (int sl = 0; sl < 8; ++sl) {
            int sg = kw * 8 + sl;
            short8_t ah = ld_coh_b128(Ab + sl * 32);
            short8_t al = ld_coh_b128(Alb + sl * 32);
#pragma unroll
            for (int g = 0; g < 3; ++g) {
                const unsigned short* bp = Bb + (size_t)(g * 32 + sg) * 512;
                short8_t bh = *(const short8_t*)bp;
                short8_t bl = *(const short8_t*)(bp + PO_S);
                acc[g] = __builtin_amdgcn_mfma_f32_16x16x32_bf16(ah, bh, acc[g], 0, 0, 0);
                acc[g] = __builtin_amdgcn_mfma_f32_16x16x32_bf16(ah, bl, acc[g], 0, 0, 0);
                acc[g] = __builtin_amdgcn_mfma_f32_16x16x32_bf16(al, bh, acc[g], 0, 0, 0);
            }
        }
#pragma unroll
        for (int g = 0; g < 3; ++g)
#pragma unroll
            for (int r = 0; r < 4; ++r)
                sm.red[kw][mw][g][(lq * 4 + r) * 16 + lr] = acc[g][r];
        __syncthreads();

        int b = tx >> 4, c = tx & 15;
        int mw2 = b >> 4, ml = b & 15;
        float gz = 0.f, gr_ = 0.f, gc = 0.f;
#pragma unroll
        for (int k2 = 0; k2 < 4; ++k2) {
            gz  += sm.red[k2][mw2][0][ml * 16 + c];
            gr_ += sm.red[k2][mw2][1][ml * 16 + c];
            gc  += sm.red[k2][mw2][2][ml * 16 + c];
        }
        int col = j * 16 + c;
        const float* gx = GX + ((size_t)b * NS + t) * G3 + col;
        float z = sigmoidf_(gx[0]      + gz  + b1[col]);
        float r = sigmoidf_(gx[NU]     + gr_ + b1[NU + col]);
        float cc = tanhf(gx[2 * NU] + r * (gc + b1[2 * NU + col]));
        // coherent 32-bit read of previous h (hi+lo), half-select
        unsigned hw = ld_coh_u32((const unsigned*)(Ah + (size_t)b * NU + (col & ~1)));
        unsigned lw = ld_coh_u32((const unsigned*)(Al + (size_t)b * NU + (col & ~1)));
        unsigned sh = (col & 1) << 4;
        float hp = bf2f((unsigned short)(hw >> sh)) + bf2f((unsigned short)(lw >> sh));
        float hn = z * hp + (1.f - z) * cc;
        st_coh_f32(enc_out + (size_t)b * NS * NU + (size_t)t * NU + col, hn);
        unsigned short hh = f2bf(hn);
        unsigned short hl = f2bf(hn - bf2f(hh));
        // pack (c, c+1) pair into one u32 coherent store (c and c+1 same wave)
        unsigned vh = hh, vl = hl;
        unsigned nh = __shfl_down(vh, 1);
        unsigned nl = __shfl_down(vl, 1);
        if (!(c & 1)) {
            st_coh_u32((unsigned*)(Oh + (size_t)b * NU + col), vh | (nh << 16));
            st_coh_u32((unsigned*)(Ol + (size_t)b * NU + col), vl | (nl << 16));
        }

        gsync(bar, ++ph * (unsigned)NB);
    }

    // initial decoder ctx from final encoder hidden (block = batch row).
    // enc_out plain reads: first plain touch this dispatch -> fresh.
    // ctx plain writes: flushed by end-of-kernel release (read next kernel).
    attn_phase<false, false>(j, tx, enc_out + (size_t)(NS - 1) * NU, NS * NU,
                             enc_out, ctx_hi, ctx_lo, sm.at.h, sm.at.sc);
}

// ---------------------------------------------------------------------------
// Persistent decoder scan: 39 x (step -> gsync -> attention -> gsync).
// Mutable ctx/hdec: sc1. Weights/gx/enc_out: plain (L2-hot whole scan).
// ---------------------------------------------------------------------------
__global__ __launch_bounds__(1024) void k_scan_dec(
    unsigned short* __restrict__ ctx_hi, unsigned short* __restrict__ ctx_lo,
    const unsigned short* __restrict__ Bp,
    const float* __restrict__ GX, const float* __restrict__ b1,
    float* __restrict__ hdec,
    unsigned short* __restrict__ Hs_hi, unsigned short* __restrict__ Hs_lo,
    const float* __restrict__ enc_out,
    unsigned* bar)
{
    __shared__ SMem sm;
    int tx = threadIdx.x;
    int j = blockIdx.x;
    int w = tx >> 6, l = tx & 63;
    int lq = l >> 4, lr = l & 15;
    int mw = w & 3, kw = w >> 2;
    const unsigned short* Bb = Bp + (size_t)j * 96 * 512 + l * 8;
    unsigned ph = 0;

#pragma unroll 1
    for (int t = 0; t < NT; ++t) {
        float4_t acc[3] = {{0,0,0,0},{0,0,0,0},{0,0,0,0}};
        const unsigned short* Ab  = ctx_hi + (size_t)(mw * 16 + lr) * NU + kw * 256 + lq * 8;
        const unsigned short* Alb = ctx_lo + (size_t)(mw * 16 + lr) * NU + kw * 256 + lq * 8;
#pragma unroll
        for (int sl = 0; sl < 8; ++sl) {
            int sg = kw * 8 + sl;
            short8_t ah = ld_coh_b128(Ab + sl * 32);
            short8_t al = ld_coh_b128(Alb + sl * 32);
#pragma unroll
            for (int g = 0; g < 3; ++g) {
                const unsigned short* bp = Bb + (size_t)(g * 32 + sg) * 512;
                short8_t bh = *(const short8_t*)bp;
                short8_t bl = *(const short8_t*)(bp + PO_S);
                acc[g] = __builtin_amdgcn_mfma_f32_16x16x32_bf16(ah, bh, acc[g], 0, 0, 0);
                acc[g] = __builtin_amdgcn_mfma_f32_16x16x32_bf16(ah, bl, acc[g], 0, 0, 0);
                acc[g] = __builtin_amdgcn_mfma_f32_16x16x32_bf16(al, bh, acc[g], 0, 0, 0);
            }
        }
#pragma unroll
        for (int g = 0; g < 3; ++g)
#pragma unroll
            for (int r = 0; r < 4; ++r)
                sm.red[kw][mw][g][(lq * 4 + r) * 16 + lr] = acc[g][r];
        __syncthreads();

        int b = tx >> 4, c = tx & 15;
        int mw2 = b >> 4, ml = b & 15;
        float gz = 0.f, gr_ = 0.f, gc = 0.f;
#pragma unroll
        for (int k2 = 0; k2 < 4; ++k2) {
            gz  += sm.red[k2][mw2][0][ml * 16 + c];
            gr_ += sm.red[k2][mw2][1][ml * 16 + c];
            gc  += sm.red[k2][mw2][2][ml * 16 + c];
        }
        int col = j * 16 + c;
        const float* gx = GX + ((size_t)b * NT + t) * G3 + col;
        float z = sigmoidf_(gx[0]  + gz  + b1[col]);
        float r = sigmoidf_(gx[NU] + gr_ + b1[NU + col]);
        float cc = tanhf(gx[2 * NU] + gc + r * b1[2 * NU + col]);
        float hn = (1.f - z) * cc;
        st_coh_f32(hdec + (size_t)b * NU + col, hn);
        size_t row = (size_t)t * NB + b;
        unsigned short hh = f2bf(hn);
        Hs_hi[row * NU + col] = hh;                       // plain: read by k_fc only
        Hs_lo[row * NU + col] = f2bf(hn - bf2f(hh));

        if (t < NT - 1) {
            gsync(bar, ++ph * (unsigned)NB);
            attn_phase<true, true>(j, tx, hdec, NU, enc_out,
                                   ctx_hi, ctx_lo, sm.at.h, sm.at.sc);
            gsync(bar, ++ph * (unsigned)NB);
        }
    }
}

// ---------------------------------------------------------------------------
// FC: 1280 blocks. XCD-aware remap: each XCD owns 16 consecutive cb values so
// its B working set (16 x 256 KB hi+lo) fits its private 4 MB L2 instead of
// being re-fetched by all 8 XCDs.
// ---------------------------------------------------------------------------
__global__ __launch_bounds__(256) void k_fc_mfma(const unsigned short* __restrict__ Ah,
                                                 const unsigned short* __restrict__ Al,
                                                 const unsigned short* __restrict__ Bp,
                                                 const float* __restrict__ bias,
                                                 float* __restrict__ out)
{
    int tx = threadIdx.x;
    int w = tx >> 6, l = tx & 63;
    int lq = l >> 4, lr = l & 15;
    int lin = blockIdx.x + blockIdx.y * gridDim.x;   // 0..1279, dispatch order
    int xcd = lin & 7;
    int slot = lin >> 3;                             // 0..159
    int cb = (xcd << 4) | (slot & 15);               // 16 cb per XCD
    int row0 = (slot >> 4) * 256 + w * 64;           // 10 M-tiles
    float4_t acc[4][4];
#pragma unroll
    for (int i = 0; i < 4; ++i)
#pragma unroll
        for (int jn = 0; jn < 4; ++jn) acc[i][jn] = (float4_t){0.f, 0.f, 0.f, 0.f};
#pragma unroll 1
    for (int s = 0; s < NU / 32; ++s) {
        short8_t ah[4], al[4];
#pragma unroll
        for (int mf = 0; mf < 4; ++mf) {
            const unsigned short* ap = Ah + (size_t)(row0 + mf * 16 + lr) * NU + s * 32 + lq * 8;
            const unsigned short* alp = Al + (size_t)(row0 + mf * 16 + lr) * NU + s * 32 + lq * 8;
            ah[mf] = *(const short8_t*)ap;
            al[mf] = *(const short8_t*)alp;
        }
#pragma unroll
        for (int nf = 0; nf < 4; ++nf) {
            const unsigned short* bp = Bp + ((((size_t)cb * 4 + nf) * 32 + s) * 64 + l) * 8;
            short8_t bh = *(const short8_t*)bp;
            short8_t bl = *(const short8_t*)(bp + PO_FC);
#pragma unroll
            for (int mf = 0; mf < 4; ++mf) {
                acc[mf][nf] = __builtin_amdgcn_mfma_f32_16x16x32_bf16(ah[mf], bh, acc[mf][nf], 0, 0, 0);
                acc[mf][nf] = __builtin_amdgcn_mfma_f32_16x16x32_bf16(ah[mf], bl, acc[mf][nf], 0, 0, 0);
                acc[mf][nf] = __builtin_amdgcn_mfma_f32_16x16x32_bf16(al[mf], bh, acc[mf][nf], 0, 0, 0);
            }
        }
    }
#pragma unroll
    for (int nf = 0; nf < 4; ++nf) {
        int v = cb * 64 + nf * 16 + lr;
        float bi = bias[v];
#pragma unroll
        for (int mf = 0; mf < 4; ++mf)
#pragma unroll
            for (int r = 0; r < 4; ++r) {
                int gr = row0 + mf * 16 + lq * 4 + r;   // Hs row = t*64 + b
                if (gr < NT * NB) {
                    int tt = gr >> 6, bb = gr & 63;
                    out[((size_t)bb * NT + tt) * NVO + v] = acc[mf][nf][r] + bi;
                }
            }
    }
}

// ---------------------------------------------------------------------------

extern "C" void kernel_launch(void* const* d_in, const int* in_sizes, int n_in,
                              void* d_out, int out_size, void* d_ws, size_t ws_size,
                              hipStream_t stream)
{
    const int*   inp     = (const int*)d_in[0];
    const int*   targ    = (const int*)d_in[1];
    const float* enc_emb = (const float*)d_in[2];
    const float* enc_Wx  = (const float*)d_in[3];
    const float* enc_Wh  = (const float*)d_in[4];
    const float* enc_b   = (const float*)d_in[5];
    const float* dec_emb = (const float*)d_in[6];
    const float* dec_Wx  = (const float*)d_in[7];
    // d_in[8] = dec_Wh: unused (multiplied by h_zero == 0 in reference)
    const float* dec_b   = (const float*)d_in[9];
    const float* fc_W    = (const float*)d_in[10];
    const float* fc_b    = (const float*)d_in[11];
    float* out = (float*)d_out;

    // ---- workspace carve (bytes) ----
    char* p = (char*)d_ws;
    float*          gx_buf = (float*)p;            // 31.46 MB live during scans
    unsigned short* Bp_fc  = (unsigned short*)p;   // 33.55 MB live after scans
    p += 33554432;
    float* enc_out = (float*)p;                  p += 10485760;  // [b][s][u] fp32
    unsigned short* h_hi0 = (unsigned short*)p;  p += 131072;
    unsigned short* h_lo0 = (unsigned short*)p;  p += 131072;
    unsigned short* h_hi1 = (unsigned short*)p;  p += 131072;
    unsigned short* h_lo1 = (unsigned short*)p;  p += 131072;
    unsigned short* ctx_hi = (unsigned short*)p; p += 131072;
    unsigned short* ctx_lo = (unsigned short*)p; p += 131072;
    float* hdec = (float*)p;                     p += 262144;
    unsigned short* Hs_hi = (unsigned short*)p;  p += 5242880;   // 2560 rows (64 pad)
    unsigned short* Hs_lo = (unsigned short*)p;  p += 5242880;
    unsigned short* Bp_enc = (unsigned short*)p; p += 12582912;
    unsigned short* Bp_dec = (unsigned short*)p; p += 12582912;
    unsigned short* Ax     = (unsigned short*)p; p += 1310720;   // gathered emb bf16
    unsigned short* Bp_gx  = (unsigned short*)p; p += 3145728;   // reused enc->dec
    unsigned* bars = (unsigned*)p;               p += 256;       // [0]=enc, [32]=dec

    // zero initial h planes (buffer 0; hi0/lo0 contiguous) + barrier counters
    hipMemsetAsync(h_hi0, 0, 262144, stream);
    hipMemsetAsync(bars, 0, 256, stream);

    // pack recurrent weights
    k_pack_step<<<dim3(64, 96), 64, 0, stream>>>(enc_Wh, Bp_enc);
    k_pack_step<<<dim3(64, 96), 64, 0, stream>>>(dec_Wx, Bp_dec);  // rows 0..1023 (ctx part)

    // ---- encoder x-path (MFMA) ----
    k_pack_b<<<dim3(G3 / 16, NE / 32), 64, 0, stream>>>(enc_Wx, G3, Bp_gx, PO_GX);
    k_gather<<<NB * NS, NE, 0, stream>>>(inp, NS, NS, enc_emb, Ax);
    k_gx_mfma<<<dim3(NB * NS / 64, 48), 256, 0, stream>>>(Ax, Bp_gx, enc_b, gx_buf);

    // ---- encoder scan: ONE persistent kernel (40 steps + ctx0) ----
    k_scan_enc<<<64, 1024, 0, stream>>>(h_hi0, h_lo0, h_hi1, h_lo1,
                                        Bp_enc, gx_buf, enc_b + G3,
                                        enc_out, ctx_hi, ctx_lo, bars);

    // ---- decoder x-path (MFMA) ----
    k_pack_b<<<dim3(G3 / 16, NE / 32), 64, 0, stream>>>(dec_Wx + (size_t)NU * G3, G3, Bp_gx, PO_GX);
    k_gather<<<NB * NT, NE, 0, stream>>>(targ, NS, NT, dec_emb, Ax);
    k_gx_mfma<<<dim3(NB * NT / 64, 48), 256, 0, stream>>>(Ax, Bp_gx, dec_b, gx_buf);

    // ---- decoder scan: ONE persistent kernel (39 steps + attn) ----
    k_scan_dec<<<64, 1024, 0, stream>>>(ctx_hi, ctx_lo, Bp_dec, gx_buf, dec_b + G3,
                                        hdec, Hs_hi, Hs_lo, enc_out, bars + 32);

    // ---- FC head ----
    k_pack_b<<<dim3(NVO / 16, NU / 32), 64, 0, stream>>>(fc_W, NVO, Bp_fc, PO_FC);
    k_fc_mfma<<<dim3(10, NVO / 64), 256, 0, stream>>>(Hs_hi, Hs_lo, Bp_fc, fc_b, out);
}

// Round 6
// 2614.113 us; speedup vs baseline: 1.4838x; 1.4838x over previous
//
#include <hip/hip_runtime.h>
#include <hip/hip_bf16.h>

#define NB 64      // batch
#define NS 40      // src len
#define NT 39      // tgt steps (T-1)
#define NE 256     // emb
#define NU 1024    // hidden
#define G3 3072    // 3*U
#define NVO 8192

typedef __attribute__((ext_vector_type(8))) short short8_t;   // 8 x bf16 frag
typedef __attribute__((ext_vector_type(4))) float float4_t;   // 4 x f32 acc

// ushort plane offsets inside two-plane packs
#define PO_S  3145728   // Bp_wh: 64 blk * 96 * 64 * 8
#define PO_GX 786432    // Bp_gx: 192 * 8 * 64 * 8

// ---------------------------------------------------------------------------
__device__ __forceinline__ unsigned short f2bf(float x) {
    union { float f; unsigned u; } v; v.f = x;
    unsigned r = v.u + 0x7fffu + ((v.u >> 16) & 1u);
    return (unsigned short)(r >> 16);
}
__device__ __forceinline__ float bf2f(unsigned short h) {
    union { float f; unsigned u; } v; v.u = ((unsigned)h) << 16; return v.f;
}
__device__ __forceinline__ float sigmoidf_(float x) { return 1.0f / (1.0f + expf(-x)); }

// ---------------------------------------------------------------------------
// Agent-scope (cross-XCD coherent) helpers, 32-bit only (round-4 proven).
// sc1 ops bypass per-XCD L2 and hit the LLC (coherence point).
// Discipline this round: mutable cross-block state is sc1-WRITTEN; readers
// use either sc1 loads (tiny buffers: hdec, barrier) or PLAIN loads of
// addresses never plain-touched before in the dispatch (rotating slots) —
// plain first-touch misses L2 and fetches the sc1 data from the LLC, then
// is L2-shared by all blocks of the XCD (8x traffic cut + normal latency).
// ---------------------------------------------------------------------------
__device__ __forceinline__ float ld_coh_f32(const float* p) {
    return __hip_atomic_load((float*)p, __ATOMIC_RELAXED, __HIP_MEMORY_SCOPE_AGENT);
}
__device__ __forceinline__ void st_coh_f32(float* p, float v) {
    __hip_atomic_store(p, v, __ATOMIC_RELAXED, __HIP_MEMORY_SCOPE_AGENT);
}

// ---------------------------------------------------------------------------
// Software grid barrier, fence-free (round-4 proven: passed, absmax OK).
// __syncthreads() drains each wave's vmcnt => sc1 stores are at the LLC
// before arrival. Monotonic counter, memset-zeroed per captured replay.
// Bounded spin: residual bugs become wrong answers, not dead containers.
// ---------------------------------------------------------------------------
__device__ __forceinline__ void gsync(unsigned* bar, unsigned goal)
{
    __syncthreads();
    if (threadIdx.x == 0) {
        __hip_atomic_fetch_add(bar, 1u, __ATOMIC_RELAXED, __HIP_MEMORY_SCOPE_AGENT);
        int spin = 0;
        while (__hip_atomic_load(bar, __ATOMIC_RELAXED, __HIP_MEMORY_SCOPE_AGENT) < goal
               && spin < 8192) {
            __builtin_amdgcn_s_sleep(1);
            ++spin;
        }
        asm volatile("" ::: "memory");
    }
    __syncthreads();
}

// ---------------------------------------------------------------------------
// Packers. k_pack_b: K x N fp32 -> B-frag hi/lo planes at planeOff.
// ---------------------------------------------------------------------------
__global__ __launch_bounds__(64) void k_pack_b(const float* __restrict__ W, int N,
                                               unsigned short* __restrict__ Bp, int planeOff)
{
    int nt = blockIdx.x, s = blockIdx.y;
    int l = threadIdx.x;
    int n = nt * 16 + (l & 15);
    int k0 = s * 32 + (l >> 4) * 8;
    size_t ob = (((size_t)nt * gridDim.y + s) * 64 + l) * 8;
#pragma unroll
    for (int jj = 0; jj < 8; ++jj) {
        float x = W[(size_t)(k0 + jj) * N + n];
        unsigned short h = f2bf(x);
        Bp[ob + jj] = h;
        Bp[planeOff + ob + jj] = f2bf(x - bf2f(h));
    }
}

// Single-plane variant (plane 0 = hi, 1 = lo residual) — for the EG weight
// two-pass (halves the live pack buffer to 6.29 MB).
__global__ __launch_bounds__(64) void k_pack_b1(const float* __restrict__ W, int N,
                                                unsigned short* __restrict__ Bp, int plane)
{
    int nt = blockIdx.x, s = blockIdx.y;
    int l = threadIdx.x;
    int n = nt * 16 + (l & 15);
    int k0 = s * 32 + (l >> 4) * 8;
    size_t ob = (((size_t)nt * gridDim.y + s) * 64 + l) * 8;
#pragma unroll
    for (int jj = 0; jj < 8; ++jj) {
        float x = W[(size_t)(k0 + jj) * N + n];
        unsigned short h = f2bf(x);
        Bp[ob + jj] = plane ? f2bf(x - bf2f(h)) : h;
    }
}

// Two separate destination buffers (FC: hi and lo planes live in different
// aliased regions).
__global__ __launch_bounds__(64) void k_pack_b2(const float* __restrict__ W, int N,
                                                unsigned short* __restrict__ Bh,
                                                unsigned short* __restrict__ Bl)
{
    int nt = blockIdx.x, s = blockIdx.y;
    int l = threadIdx.x;
    int n = nt * 16 + (l & 15);
    int k0 = s * 32 + (l >> 4) * 8;
    size_t ob = (((size_t)nt * gridDim.y + s) * 64 + l) * 8;
#pragma unroll
    for (int jj = 0; jj < 8; ++jj) {
        float x = W[(size_t)(k0 + jj) * N + n];
        unsigned short h = f2bf(x);
        Bh[ob + jj] = h;
        Bl[ob + jj] = f2bf(x - bf2f(h));
    }
}

// Step-weight packer (encoder Wh): block j owns cols {g*1024 + 16j..+16}.
__global__ __launch_bounds__(64) void k_pack_step(const float* __restrict__ W,
                                                  unsigned short* __restrict__ Bp)
{
    int j = blockIdx.x;
    int q = blockIdx.y;            // g*32 + s
    int g = q >> 5, s = q & 31;
    int l = threadIdx.x;
    int n = g * NU + j * 16 + (l & 15);
    int k0 = s * 32 + (l >> 4) * 8;
    size_t ob = (((size_t)j * 96 + q) * 64 + l) * 8;
#pragma unroll
    for (int jj = 0; jj < 8; ++jj) {
        float x = W[(size_t)(k0 + jj) * G3 + n];
        unsigned short h = f2bf(x);
        Bp[ob + jj] = h;
        Bp[PO_S + ob + jj] = f2bf(x - bf2f(h));
    }
}

// Gather embeddings -> bf16 plane. grid (rows), block 256 (= NE).
__global__ __launch_bounds__(256) void k_gather(const int* __restrict__ idx,
                                                int cols_total, int cols_used,
                                                const float* __restrict__ emb,
                                                unsigned short* __restrict__ Ax)
{
    int row = blockIdx.x;
    int b = row / cols_used, c = row - b * cols_used;
    int tok = idx[b * cols_total + c];
    int k = threadIdx.x;
    Ax[(size_t)row * NE + k] = f2bf(emb[(size_t)tok * NE + k]);
}

// GX GEMM: out[row][col] = Ax[row][:256] @ W + bias. grid (M/64, 48), block 256.
__global__ __launch_bounds__(256) void k_gx_mfma(const unsigned short* __restrict__ Ax,
                                                 const unsigned short* __restrict__ Bp,
                                                 const float* __restrict__ bias,
                                                 float* __restrict__ out)
{
    int tx = threadIdx.x;
    int w = tx >> 6, l = tx & 63;
    int lq = l >> 4, lr = l & 15;
    int row0 = blockIdx.x * 64 + w * 16;
    int cb = blockIdx.y;
    float4_t acc[4] = {{0,0,0,0},{0,0,0,0},{0,0,0,0},{0,0,0,0}};
    const unsigned short* Ab = Ax + (size_t)(row0 + lr) * NE + lq * 8;
#pragma unroll
    for (int s = 0; s < 8; ++s) {
        short8_t ah = *(const short8_t*)(Ab + s * 32);
#pragma unroll
        for (int nf = 0; nf < 4; ++nf) {
            const unsigned short* bp = Bp + ((((size_t)cb * 4 + nf) * 8 + s) * 64 + l) * 8;
            short8_t bh = *(const short8_t*)bp;
            short8_t bl = *(const short8_t*)(bp + PO_GX);
            acc[nf] = __builtin_amdgcn_mfma_f32_16x16x32_bf16(ah, bh, acc[nf], 0, 0, 0);
            acc[nf] = __builtin_amdgcn_mfma_f32_16x16x32_bf16(ah, bl, acc[nf], 0, 0, 0);
        }
    }
#pragma unroll
    for (int nf = 0; nf < 4; ++nf) {
        int col = cb * 64 + nf * 16 + lr;
        float bi = bias[col];
#pragma unroll
        for (int r = 0; r < 4; ++r) {
            int gr = row0 + lq * 4 + r;
            out[(size_t)gr * G3 + col] = acc[nf][r] + bi;
        }
    }
}

// ---------------------------------------------------------------------------
// EG GEMM: EG[b][colG3][s] = enc_out[b][s][:] @ Wx_u. Two passes over the
// same single-plane weight buffer: PASS 0 (B = hi): A_hi*B + A_lo*B, store;
// PASS 1 (B = lo): A_hi*B, accumulate. Same 3 products as the proven hi/lo
// scheme, summed in fp32.
// ---------------------------------------------------------------------------
template<int PASS>
__global__ __launch_bounds__(256) void k_eg_mfma(const float* __restrict__ enc_out,
                                                 const unsigned short* __restrict__ Bp,
                                                 float* __restrict__ EG)
{
    int tx = threadIdx.x;
    int w = tx >> 6, l = tx & 63;
    int lq = l >> 4, lr = l & 15;
    int row0 = blockIdx.x * 64 + w * 16;
    int cb = blockIdx.y;
    float4_t acc[4] = {{0,0,0,0},{0,0,0,0},{0,0,0,0},{0,0,0,0}};
    const float* Ab = enc_out + (size_t)(row0 + lr) * NU + lq * 8;
#pragma unroll 1
    for (int s = 0; s < NU / 32; ++s) {
        float4_t f0 = *(const float4_t*)(Ab + s * 32);
        float4_t f1 = *(const float4_t*)(Ab + s * 32 + 4);
        short8_t ah, al;
#pragma unroll
        for (int jj = 0; jj < 4; ++jj) {
            unsigned short h0 = f2bf(f0[jj]);
            ah[jj] = (short)h0; al[jj] = (short)f2bf(f0[jj] - bf2f(h0));
            unsigned short h1 = f2bf(f1[jj]);
            ah[jj + 4] = (short)h1; al[jj + 4] = (short)f2bf(f1[jj] - bf2f(h1));
        }
#pragma unroll
        for (int nf = 0; nf < 4; ++nf) {
            const unsigned short* bp = Bp + ((((size_t)cb * 4 + nf) * 32 + s) * 64 + l) * 8;
            short8_t bv = *(const short8_t*)bp;
            acc[nf] = __builtin_amdgcn_mfma_f32_16x16x32_bf16(ah, bv, acc[nf], 0, 0, 0);
            if (PASS == 0)
                acc[nf] = __builtin_amdgcn_mfma_f32_16x16x32_bf16(al, bv, acc[nf], 0, 0, 0);
        }
    }
#pragma unroll
    for (int nf = 0; nf < 4; ++nf) {
        int v = cb * 64 + nf * 16 + lr;
#pragma unroll
        for (int r = 0; r < 4; ++r) {
            int gr = row0 + lq * 4 + r;          // rb = b*40 + s
            int b2 = gr / NS, s2 = gr - b2 * NS;
            size_t o = ((size_t)b2 * G3 + v) * NS + s2;
            if (PASS == 0) EG[o] = acc[nf][r];
            else           EG[o] += acc[nf][r];
        }
    }
}

// ---------------------------------------------------------------------------
// Attention scores (1024 thr, block = batch row b): h·enc_out -> softmax ->
// w[b][0..40]. COH_H: hsrc sc1-read (decoder hdec). COH_W: w sc1-written
// (read PLAIN next phase as a fresh slot).
// ---------------------------------------------------------------------------
template<bool COH_H, bool COH_W>
__device__ __forceinline__ void attn_scores(int b, int tx,
    const float* __restrict__ hsrc, int hstride,
    const float* __restrict__ enc_out, float* __restrict__ w_out,
    float* h_sh, float* sc_sh)
{
    int wave = tx >> 6, lane = tx & 63;
    h_sh[tx] = COH_H ? ld_coh_f32(hsrc + (size_t)b * hstride + tx)
                     : hsrc[(size_t)b * hstride + tx];
    __syncthreads();
    const float* eb = enc_out + (size_t)b * NS * NU;
    for (int s = wave; s < NS; s += 16) {
        const float* es = eb + (size_t)s * NU;
        float p = 0.f;
#pragma unroll
        for (int q = 0; q < NU / 64; ++q) p += h_sh[lane + q * 64] * es[lane + q * 64];
#pragma unroll
        for (int off = 32; off > 0; off >>= 1) p += __shfl_down(p, off);
        if (lane == 0) sc_sh[s] = p;
    }
    __syncthreads();
    if (wave == 0) {
        float v = (lane < NS) ? sc_sh[lane] : -3.0e38f;
        float m = v;
#pragma unroll
        for (int off = 32; off > 0; off >>= 1) m = fmaxf(m, __shfl_down(m, off));
        m = __shfl(m, 0);
        float e = (lane < NS) ? expf(v - m) : 0.f;
        float ss = e;
#pragma unroll
        for (int off = 32; off > 0; off >>= 1) ss += __shfl_down(ss, off);
        ss = __shfl(ss, 0);
        if (lane < NS) {
            float wv = e / ss;
            if (COH_W) st_coh_f32(w_out + (size_t)b * NS + lane, wv);
            else       w_out[(size_t)b * NS + lane] = wv;
        }
    }
    __syncthreads();
}

// ---------------------------------------------------------------------------
union SMem {
    float red[4][4][3][256];                  // 48 KB  [kw][mw][g][16x16]
    struct { float h[NU]; float sc[64]; } at;
};

// ---------------------------------------------------------------------------
// Persistent encoder scan (64 blocks x 1024). h state lives in enc_out
// itself: step t sc1-writes enc_out[:,t,:]; step t+1 PLAIN-reads it (first
// plain touch => fresh from LLC, then L2-shared by the XCD's 8 blocks).
// A-fragments split hi/lo in-register from fp32. t=0: h=0, MFMA skipped.
// Weights/gx: plain, L2-hot. LDS 48 KB.
// ---------------------------------------------------------------------------
__global__ __launch_bounds__(1024) void k_scan_enc(
    const unsigned short* __restrict__ Bp,
    const float* __restrict__ GX, const float* __restrict__ b1,
    float* __restrict__ enc_out,
    float* __restrict__ w0_out,
    unsigned* bar)
{
    __shared__ SMem sm;
    int tx = threadIdx.x;
    int j = blockIdx.x;
    int w = tx >> 6, l = tx & 63;
    int lq = l >> 4, lr = l & 15;
    int mw = w & 3, kw = w >> 2;
    const unsigned short* Bb = Bp + (size_t)j * 96 * 512 + l * 8;
    unsigned ph = 0;

#pragma unroll 1
    for (int t = 0; t < NS; ++t) {
        float4_t acc[3] = {{0,0,0,0},{0,0,0,0},{0,0,0,0}};
        if (t > 0) {
            const float* Ap = enc_out + ((size_t)(mw * 16 + lr) * NS + (t - 1)) * NU
                            + kw * 256 + lq * 8;
#pragma unroll
            for (int sl = 0; sl < 8; ++sl) {
                float4_t f0 = *(const float4_t*)(Ap + sl * 32);
                float4_t f1 = *(const float4_t*)(Ap + sl * 32 + 4);
                short8_t ah, al;
#pragma unroll
                for (int jj = 0; jj < 4; ++jj) {
                    unsigned short h0 = f2bf(f0[jj]);
                    ah[jj] = (short)h0; al[jj] = (short)f2bf(f0[jj] - bf2f(h0));
                    unsigned short h1 = f2bf(f1[jj]);
                    ah[jj + 4] = (short)h1; al[jj + 4] = (short)f2bf(f1[jj] - bf2f(h1));
                }
                int sg = kw * 8 + sl;
#pragma unroll
                for (int g = 0; g < 3; ++g) {
                    const unsigned short* bp = Bb + (size_t)(g * 32 + sg) * 512;
                    short8_t bh = *(const short8_t*)bp;
                    short8_t bl = *(const short8_t*)(bp + PO_S);
                    acc[g] = __builtin_amdgcn_mfma_f32_16x16x32_bf16(ah, bh, acc[g], 0, 0, 0);
                    acc[g] = __builtin_amdgcn_mfma_f32_16x16x32_bf16(ah, bl, acc[g], 0, 0, 0);
                    acc[g] = __builtin_amdgcn_mfma_f32_16x16x32_bf16(al, bh, acc[g], 0, 0, 0);
                }
            }
        }
#pragma unroll
        for (int g = 0; g < 3; ++g)
#pragma unroll
            for (int r = 0; r < 4; ++r)
                sm.red[kw][mw][g][(lq * 4 + r) * 16 + lr] = acc[g][r];
        __syncthreads();

        int b = tx >> 4, c = tx & 15;
        int mw2 = b >> 4, ml = b & 15;
        float gz = 0.f, gr_ = 0.f, gc = 0.f;
#pragma unroll
        for (int k2 = 0; k2 < 4; ++k2) {
            gz  += sm.red[k2][mw2][0][ml * 16 + c];
            gr_ += sm.red[k2][mw2][1][ml * 16 + c];
            gc  += sm.red[k2][mw2][2][ml * 16 + c];
        }
        int col = j * 16 + c;
        const float* gx = GX + ((size_t)b * NS + t) * G3 + col;
        float z = sigmoidf_(gx[0]      + gz  + b1[col]);
        float r = sigmoidf_(gx[NU]     + gr_ + b1[NU + col]);
        float cc = tanhf(gx[2 * NU] + r * (gc + b1[2 * NU + col]));
        float hp = (t > 0) ? enc_out[((size_t)b * NS + (t - 1)) * NU + col] : 0.f;
        float hn = z * hp + (1.f - z) * cc;
        st_coh_f32(enc_out + ((size_t)b * NS + t) * NU + col, hn);

        gsync(bar, ++ph * (unsigned)NB);
    }

    // initial decoder attention weights -> w slot 0 (plain; cross-dispatch
    // flush publishes it). enc_out[:,39,:] is a fresh plain touch here.
    attn_scores<false, false>(j, tx, enc_out + (size_t)(NS - 1) * NU, NS * NU,
                              enc_out, w0_out, sm.at.h, sm.at.sc);
}

// ---------------------------------------------------------------------------
// Persistent decoder scan, LINEARIZED (EG): per step
//   A: gates = sum_s w[t][b,s]*EG[b,col,s] + gx + bias -> h (VALU only)
//   B: scores = h . enc_out -> softmax -> w[t+1]
// w rotates through NT slots: sc1-written in B, PLAIN-read (fresh) in A.
// EG/gx/enc_out plain, L2-hot. hdec: sc1 (4 KB/block read in B).
// ---------------------------------------------------------------------------
__global__ __launch_bounds__(1024) void k_scan_dec(
    const float* __restrict__ EG,
    const float* __restrict__ GX, const float* __restrict__ b1,
    float* __restrict__ hdec,
    unsigned short* __restrict__ Hs_hi, unsigned short* __restrict__ Hs_lo,
    const float* __restrict__ enc_out,
    float* __restrict__ w_slots,
    unsigned* bar)
{
    __shared__ struct { float wrow[NB * NS]; float h[NU]; float sc[64]; } sm;
    int tx = threadIdx.x;
    int j = blockIdx.x;
    int b = tx >> 4, c = tx & 15;
    int col = j * 16 + c;
    const float* egz = EG + ((size_t)b * G3 + col) * NS;
    const float* egr = egz + (size_t)NU * NS;
    const float* egc = egz + (size_t)(2 * NU) * NS;
    unsigned ph = 0;

#pragma unroll 1
    for (int t = 0; t < NT; ++t) {
        // ---- phase A: stage w slot t into LDS (plain, fresh), gates, h ----
        const float* wsl = w_slots + (size_t)t * (NB * NS);
        for (int i = tx; i < NB * NS; i += 1024) sm.wrow[i] = wsl[i];
        __syncthreads();

        const float* wr = sm.wrow + b * NS;
        float ez = 0.f, er = 0.f, ec = 0.f;
#pragma unroll
        for (int s4 = 0; s4 < NS / 4; ++s4) {
            float4_t wv = *(const float4_t*)(wr + s4 * 4);
            float4_t vz = *(const float4_t*)(egz + s4 * 4);
            float4_t vr = *(const float4_t*)(egr + s4 * 4);
            float4_t vc = *(const float4_t*)(egc + s4 * 4);
            ez += wv[0]*vz[0] + wv[1]*vz[1] + wv[2]*vz[2] + wv[3]*vz[3];
            er += wv[0]*vr[0] + wv[1]*vr[1] + wv[2]*vr[2] + wv[3]*vr[3];
            ec += wv[0]*vc[0] + wv[1]*vc[1] + wv[2]*vc[2] + wv[3]*vc[3];
        }
        const float* gx = GX + ((size_t)b * NT + t) * G3 + col;
        float z = sigmoidf_(gx[0]  + ez + b1[col]);
        float r = sigmoidf_(gx[NU] + er + b1[NU + col]);
        float cc = tanhf(gx[2 * NU] + ec + r * b1[2 * NU + col]);
        float hn = (1.f - z) * cc;
        st_coh_f32(hdec + (size_t)b * NU + col, hn);
        size_t row = (size_t)t * NB + b;
        unsigned short hh = f2bf(hn);
        Hs_hi[row * NU + col] = hh;                 // plain: read by k_fc only
        Hs_lo[row * NU + col] = f2bf(hn - bf2f(hh));

        if (t < NT - 1) {
            gsync(bar, ++ph * (unsigned)NB);
            attn_scores<true, true>(j, tx, hdec, NU, enc_out,
                                    w_slots + (size_t)(t + 1) * (NB * NS),
                                    sm.h, sm.sc);
            gsync(bar, ++ph * (unsigned)NB);
        }
    }
}

// ---------------------------------------------------------------------------
// FC: 1280 blocks, XCD-aware remap; hi/lo weight planes in separate buffers.
// ---------------------------------------------------------------------------
__global__ __launch_bounds__(256) void k_fc_mfma(const unsigned short* __restrict__ Ah,
                                                 const unsigned short* __restrict__ Al,
                                                 const unsigned short* __restrict__ Bh,
                                                 const unsigned short* __restrict__ Bl,
                                                 const float* __restrict__ bias,
                                                 float* __restrict__ out)
{
    int tx = threadIdx.x;
    int w = tx >> 6, l = tx & 63;
    int lq = l >> 4, lr = l & 15;
    int lin = blockIdx.x + blockIdx.y * gridDim.x;
    int xcd = lin & 7;
    int slot = lin >> 3;
    int cb = (xcd << 4) | (slot & 15);
    int row0 = (slot >> 4) * 256 + w * 64;
    float4_t acc[4][4];
#pragma unroll
    for (int i = 0; i < 4; ++i)
#pragma unroll
        for (int jn = 0; jn < 4; ++jn) acc[i][jn] = (float4_t){0.f, 0.f, 0.f, 0.f};
#pragma unroll 1
    for (int s = 0; s < NU / 32; ++s) {
        short8_t ah[4], al[4];
#pragma unroll
        for (int mf = 0; mf < 4; ++mf) {
            const unsigned short* ap = Ah + (size_t)(row0 + mf * 16 + lr) * NU + s * 32 + lq * 8;
            const unsigned short* alp = Al + (size_t)(row0 + mf * 16 + lr) * NU + s * 32 + lq * 8;
            ah[mf] = *(const short8_t*)ap;
            al[mf] = *(const short8_t*)alp;
        }
#pragma unroll
        for (int nf = 0; nf < 4; ++nf) {
            size_t idx = ((((size_t)cb * 4 + nf) * 32 + s) * 64 + l) * 8;
            short8_t bh = *(const short8_t*)(Bh + idx);
            short8_t bl = *(const short8_t*)(Bl + idx);
#pragma unroll
            for (int mf = 0; mf < 4; ++mf) {
                acc[mf][nf] = __builtin_amdgcn_mfma_f32_16x16x32_bf16(ah[mf], bh, acc[mf][nf], 0, 0, 0);
                acc[mf][nf] = __builtin_amdgcn_mfma_f32_16x16x32_bf16(ah[mf], bl, acc[mf][nf], 0, 0, 0);
                acc[mf][nf] = __builtin_amdgcn_mfma_f32_16x16x32_bf16(al[mf], bh, acc[mf][nf], 0, 0, 0);
            }
        }
    }
#pragma unroll
    for (int nf = 0; nf < 4; ++nf) {
        int v = cb * 64 + nf * 16 + lr;
        float bi = bias[v];
#pragma unroll
        for (int mf = 0; mf < 4; ++mf)
#pragma unroll
            for (int r = 0; r < 4; ++r) {
                int gr = row0 + mf * 16 + lq * 4 + r;   // Hs row = t*64 + b
                if (gr < NT * NB) {
                    int tt = gr >> 6, bb = gr & 63;
                    out[((size_t)bb * NT + tt) * NVO + v] = acc[mf][nf][r] + bi;
                }
            }
    }
}

// ---------------------------------------------------------------------------

extern "C" void kernel_launch(void* const* d_in, const int* in_sizes, int n_in,
                              void* d_out, int out_size, void* d_ws, size_t ws_size,
                              hipStream_t stream)
{
    const int*   inp     = (const int*)d_in[0];
    const int*   targ    = (const int*)d_in[1];
    const float* enc_emb = (const float*)d_in[2];
    const float* enc_Wx  = (const float*)d_in[3];
    const float* enc_Wh  = (const float*)d_in[4];
    const float* enc_b   = (const float*)d_in[5];
    const float* dec_emb = (const float*)d_in[6];
    const float* dec_Wx  = (const float*)d_in[7];
    // d_in[8] = dec_Wh: unused (multiplied by h_zero == 0 in reference)
    const float* dec_b   = (const float*)d_in[9];
    const float* fc_W    = (const float*)d_in[10];
    const float* fc_b    = (const float*)d_in[11];
    float* out = (float*)d_out;

    // ---- workspace carve: TOTAL 84,558,080 B < proven 85,197,056 B ----
    char* p = (char*)d_ws;
    // R1 (31,457,280): gx_buf (enc, then dec) -> Bp_fc HI plane after dec scan
    float*          gx_buf = (float*)p;
    unsigned short* BfcH   = (unsigned short*)p;
    p += 31457280;
    // R2 (10,485,760): enc_out fp32 [b][s][u]
    float* enc_out = (float*)p;  p += 10485760;
    // R3 (10,485,760): Bp_egw single plane (6.29 MB, eg passes) -> Hs hi/lo
    unsigned short* Bp_egw = (unsigned short*)p;
    unsigned short* Hs_hi  = (unsigned short*)p;
    unsigned short* Hs_lo  = Hs_hi + 2621440;   // +5,242,880 B
    p += 10485760;
    // R4 (31,457,280): [Bp_wh 12.58 | Ax 1.31 | Bp_gx 3.15] -> EG -> Bp_fc LO
    char* r4 = p;
    unsigned short* Bp_wh = (unsigned short*)r4;
    unsigned short* Ax    = (unsigned short*)(r4 + 12582912);
    unsigned short* Bp_gx = (unsigned short*)(r4 + 13893632);
    float*          EG    = (float*)r4;
    unsigned short* BfcL  = (unsigned short*)r4;
    p += 31457280;
    // R5: w slots (40 x 10,240 B) + hdec + barrier counters
    float* w_slots = (float*)p; p += 409600;
    float* hdec    = (float*)p; p += 262144;
    unsigned* bars = (unsigned*)p; p += 256;

    hipMemsetAsync(bars, 0, 256, stream);

    // pack encoder recurrent weights
    k_pack_step<<<dim3(64, 96), 64, 0, stream>>>(enc_Wh, Bp_wh);

    // ---- encoder x-path ----
    k_pack_b<<<dim3(G3 / 16, NE / 32), 64, 0, stream>>>(enc_Wx, G3, Bp_gx, PO_GX);
    k_gather<<<NB * NS, NE, 0, stream>>>(inp, NS, NS, enc_emb, Ax);
    k_gx_mfma<<<dim3(NB * NS / 64, 48), 256, 0, stream>>>(Ax, Bp_gx, enc_b, gx_buf);

    // ---- encoder scan: ONE persistent kernel (40 steps + w0) ----
    k_scan_enc<<<64, 1024, 0, stream>>>(Bp_wh, gx_buf, enc_b + G3,
                                        enc_out, w_slots, bars);

    // ---- decoder x-path ----
    k_pack_b<<<dim3(G3 / 16, NE / 32), 64, 0, stream>>>(dec_Wx + (size_t)NU * G3, G3, Bp_gx, PO_GX);
    k_gather<<<NB * NT, NE, 0, stream>>>(targ, NS, NT, dec_emb, Ax);
    k_gx_mfma<<<dim3(NB * NT / 64, 48), 256, 0, stream>>>(Ax, Bp_gx, dec_b, gx_buf);

    // ---- EG precompute (two passes; writes clobber Bp_wh/Ax/Bp_gx: all dead) ----
    k_pack_b1<<<dim3(G3 / 16, NU / 32), 64, 0, stream>>>(dec_Wx, G3, Bp_egw, 0);
    k_eg_mfma<0><<<dim3(NB * NS / 64, 48), 256, 0, stream>>>(enc_out, Bp_egw, EG);
    k_pack_b1<<<dim3(G3 / 16, NU / 32), 64, 0, stream>>>(dec_Wx, G3, Bp_egw, 1);
    k_eg_mfma<1><<<dim3(NB * NS / 64, 48), 256, 0, stream>>>(enc_out, Bp_egw, EG);

    // ---- decoder scan: ONE persistent kernel (39 linearized steps) ----
    k_scan_dec<<<64, 1024, 0, stream>>>(EG, gx_buf, dec_b + G3,
                                        hdec, Hs_hi, Hs_lo, enc_out, w_slots, bars + 32);

    // ---- FC head (hi plane over gx region, lo plane over EG region) ----
    k_pack_b2<<<dim3(NVO / 16, NU / 32), 64, 0, stream>>>(fc_W, NVO, BfcH, BfcL);
    k_fc_mfma<<<dim3(10, NVO / 64), 256, 0, stream>>>(Hs_hi, Hs_lo, BfcH, BfcL, fc_b, out);
}

// Round 7
// 1778.554 us; speedup vs baseline: 2.1809x; 1.4698x over previous
//
#include <hip/hip_runtime.h>
#include <hip/hip_bf16.h>

#define NB 64      // batch
#define NS 40      // src len
#define NT 39      // tgt steps (T-1)
#define NE 256     // emb
#define NU 1024    // hidden
#define G3 3072    // 3*U
#define NVO 8192

typedef __attribute__((ext_vector_type(8))) short short8_t;   // 8 x bf16 frag
typedef __attribute__((ext_vector_type(4))) float float4_t;   // 4 x f32 acc

// ushort plane offsets inside two-plane packs
#define PO_S  3145728   // Bp_wh: 64 blk * 96 * 64 * 8
#define PO_GX 786432    // Bp_gx: 192 * 8 * 64 * 8

// ---------------------------------------------------------------------------
__device__ __forceinline__ unsigned short f2bf(float x) {
    union { float f; unsigned u; } v; v.f = x;
    unsigned r = v.u + 0x7fffu + ((v.u >> 16) & 1u);
    return (unsigned short)(r >> 16);
}
__device__ __forceinline__ float bf2f(unsigned short h) {
    union { float f; unsigned u; } v; v.u = ((unsigned)h) << 16; return v.f;
}
__device__ __forceinline__ float sigmoidf_(float x) { return 1.0f / (1.0f + expf(-x)); }

// ---------------------------------------------------------------------------
// Agent-scope helpers (round-4/6 proven): sc1 ops bypass per-XCD L2, hit LLC.
// Used ONLY by the encoder scan (true recurrence). Decoder is now barrier-
// free and uses none of this.
// ---------------------------------------------------------------------------
__device__ __forceinline__ float ld_coh_f32(const float* p) {
    return __hip_atomic_load((float*)p, __ATOMIC_RELAXED, __HIP_MEMORY_SCOPE_AGENT);
}
__device__ __forceinline__ void st_coh_f32(float* p, float v) {
    __hip_atomic_store(p, v, __ATOMIC_RELAXED, __HIP_MEMORY_SCOPE_AGENT);
}

// ---------------------------------------------------------------------------
// Software grid barrier, fence-free (round-4/6 proven). Encoder only.
// ---------------------------------------------------------------------------
__device__ __forceinline__ void gsync(unsigned* bar, unsigned goal)
{
    __syncthreads();
    if (threadIdx.x == 0) {
        __hip_atomic_fetch_add(bar, 1u, __ATOMIC_RELAXED, __HIP_MEMORY_SCOPE_AGENT);
        int spin = 0;
        while (__hip_atomic_load(bar, __ATOMIC_RELAXED, __HIP_MEMORY_SCOPE_AGENT) < goal
               && spin < 8192) {
            __builtin_amdgcn_s_sleep(1);
            ++spin;
        }
        asm volatile("" ::: "memory");
    }
    __syncthreads();
}

// ---------------------------------------------------------------------------
// Packers.
// ---------------------------------------------------------------------------
__global__ __launch_bounds__(64) void k_pack_b(const float* __restrict__ W, int N,
                                               unsigned short* __restrict__ Bp, int planeOff)
{
    int nt = blockIdx.x, s = blockIdx.y;
    int l = threadIdx.x;
    int n = nt * 16 + (l & 15);
    int k0 = s * 32 + (l >> 4) * 8;
    size_t ob = (((size_t)nt * gridDim.y + s) * 64 + l) * 8;
#pragma unroll
    for (int jj = 0; jj < 8; ++jj) {
        float x = W[(size_t)(k0 + jj) * N + n];
        unsigned short h = f2bf(x);
        Bp[ob + jj] = h;
        Bp[planeOff + ob + jj] = f2bf(x - bf2f(h));
    }
}

// Single-plane variant (0 = hi, 1 = lo residual) for the EG weight two-pass.
__global__ __launch_bounds__(64) void k_pack_b1(const float* __restrict__ W, int N,
                                                unsigned short* __restrict__ Bp, int plane)
{
    int nt = blockIdx.x, s = blockIdx.y;
    int l = threadIdx.x;
    int n = nt * 16 + (l & 15);
    int k0 = s * 32 + (l >> 4) * 8;
    size_t ob = (((size_t)nt * gridDim.y + s) * 64 + l) * 8;
#pragma unroll
    for (int jj = 0; jj < 8; ++jj) {
        float x = W[(size_t)(k0 + jj) * N + n];
        unsigned short h = f2bf(x);
        Bp[ob + jj] = plane ? f2bf(x - bf2f(h)) : h;
    }
}

// Two separate destination buffers (FC hi/lo planes live in aliased regions).
__global__ __launch_bounds__(64) void k_pack_b2(const float* __restrict__ W, int N,
                                                unsigned short* __restrict__ Bh,
                                                unsigned short* __restrict__ Bl)
{
    int nt = blockIdx.x, s = blockIdx.y;
    int l = threadIdx.x;
    int n = nt * 16 + (l & 15);
    int k0 = s * 32 + (l >> 4) * 8;
    size_t ob = (((size_t)nt * gridDim.y + s) * 64 + l) * 8;
#pragma unroll
    for (int jj = 0; jj < 8; ++jj) {
        float x = W[(size_t)(k0 + jj) * N + n];
        unsigned short h = f2bf(x);
        Bh[ob + jj] = h;
        Bl[ob + jj] = f2bf(x - bf2f(h));
    }
}

// Step-weight packer (encoder Wh): block j owns cols {g*1024 + 16j..+16}.
__global__ __launch_bounds__(64) void k_pack_step(const float* __restrict__ W,
                                                  unsigned short* __restrict__ Bp)
{
    int j = blockIdx.x;
    int q = blockIdx.y;            // g*32 + s
    int g = q >> 5, s = q & 31;
    int l = threadIdx.x;
    int n = g * NU + j * 16 + (l & 15);
    int k0 = s * 32 + (l >> 4) * 8;
    size_t ob = (((size_t)j * 96 + q) * 64 + l) * 8;
#pragma unroll
    for (int jj = 0; jj < 8; ++jj) {
        float x = W[(size_t)(k0 + jj) * G3 + n];
        unsigned short h = f2bf(x);
        Bp[ob + jj] = h;
        Bp[PO_S + ob + jj] = f2bf(x - bf2f(h));
    }
}

// Gather embeddings -> bf16 plane. grid (rows), block 256 (= NE).
__global__ __launch_bounds__(256) void k_gather(const int* __restrict__ idx,
                                                int cols_total, int cols_used,
                                                const float* __restrict__ emb,
                                                unsigned short* __restrict__ Ax)
{
    int row = blockIdx.x;
    int b = row / cols_used, c = row - b * cols_used;
    int tok = idx[b * cols_total + c];
    int k = threadIdx.x;
    Ax[(size_t)row * NE + k] = f2bf(emb[(size_t)tok * NE + k]);
}

// GX GEMM: out[row][col] = Ax[row][:256] @ W + bias. grid (M/64, 48), block 256.
__global__ __launch_bounds__(256) void k_gx_mfma(const unsigned short* __restrict__ Ax,
                                                 const unsigned short* __restrict__ Bp,
                                                 const float* __restrict__ bias,
                                                 float* __restrict__ out)
{
    int tx = threadIdx.x;
    int w = tx >> 6, l = tx & 63;
    int lq = l >> 4, lr = l & 15;
    int row0 = blockIdx.x * 64 + w * 16;
    int cb = blockIdx.y;
    float4_t acc[4] = {{0,0,0,0},{0,0,0,0},{0,0,0,0},{0,0,0,0}};
    const unsigned short* Ab = Ax + (size_t)(row0 + lr) * NE + lq * 8;
#pragma unroll
    for (int s = 0; s < 8; ++s) {
        short8_t ah = *(const short8_t*)(Ab + s * 32);
#pragma unroll
        for (int nf = 0; nf < 4; ++nf) {
            const unsigned short* bp = Bp + ((((size_t)cb * 4 + nf) * 8 + s) * 64 + l) * 8;
            short8_t bh = *(const short8_t*)bp;
            short8_t bl = *(const short8_t*)(bp + PO_GX);
            acc[nf] = __builtin_amdgcn_mfma_f32_16x16x32_bf16(ah, bh, acc[nf], 0, 0, 0);
            acc[nf] = __builtin_amdgcn_mfma_f32_16x16x32_bf16(ah, bl, acc[nf], 0, 0, 0);
        }
    }
#pragma unroll
    for (int nf = 0; nf < 4; ++nf) {
        int col = cb * 64 + nf * 16 + lr;
        float bi = bias[col];
#pragma unroll
        for (int r = 0; r < 4; ++r) {
            int gr = row0 + lq * 4 + r;
            out[(size_t)gr * G3 + col] = acc[nf][r] + bi;
        }
    }
}

// ---------------------------------------------------------------------------
// EG GEMM: EG[rb][v] = enc_out[rb][:] @ Wx_u  (rb = b*40+s, natural layout so
// the decoder's per-s gate loads are lane-coalesced). Two passes over one
// single-plane weight buffer: PASS0 (B=hi): A_hi*B + A_lo*B, store; PASS1
// (B=lo): A_hi*B, accumulate.
// ---------------------------------------------------------------------------
template<int PASS>
__global__ __launch_bounds__(256) void k_eg_mfma(const float* __restrict__ enc_out,
                                                 const unsigned short* __restrict__ Bp,
                                                 float* __restrict__ EG)
{
    int tx = threadIdx.x;
    int w = tx >> 6, l = tx & 63;
    int lq = l >> 4, lr = l & 15;
    int row0 = blockIdx.x * 64 + w * 16;
    int cb = blockIdx.y;
    float4_t acc[4] = {{0,0,0,0},{0,0,0,0},{0,0,0,0},{0,0,0,0}};
    const float* Ab = enc_out + (size_t)(row0 + lr) * NU + lq * 8;
#pragma unroll 1
    for (int s = 0; s < NU / 32; ++s) {
        float4_t f0 = *(const float4_t*)(Ab + s * 32);
        float4_t f1 = *(const float4_t*)(Ab + s * 32 + 4);
        short8_t ah, al;
#pragma unroll
        for (int jj = 0; jj < 4; ++jj) {
            unsigned short h0 = f2bf(f0[jj]);
            ah[jj] = (short)h0; al[jj] = (short)f2bf(f0[jj] - bf2f(h0));
            unsigned short h1 = f2bf(f1[jj]);
            ah[jj + 4] = (short)h1; al[jj + 4] = (short)f2bf(f1[jj] - bf2f(h1));
        }
#pragma unroll
        for (int nf = 0; nf < 4; ++nf) {
            const unsigned short* bp = Bp + ((((size_t)cb * 4 + nf) * 32 + s) * 64 + l) * 8;
            short8_t bv = *(const short8_t*)bp;
            acc[nf] = __builtin_amdgcn_mfma_f32_16x16x32_bf16(ah, bv, acc[nf], 0, 0, 0);
            if (PASS == 0)
                acc[nf] = __builtin_amdgcn_mfma_f32_16x16x32_bf16(al, bv, acc[nf], 0, 0, 0);
        }
    }
#pragma unroll
    for (int nf = 0; nf < 4; ++nf) {
        int v = cb * 64 + nf * 16 + lr;
#pragma unroll
        for (int r = 0; r < 4; ++r) {
            int gr = row0 + lq * 4 + r;          // rb = b*40 + s
            size_t o = (size_t)gr * G3 + v;
            if (PASS == 0) EG[o] = acc[nf][r];
            else           EG[o] += acc[nf][r];
        }
    }
}

// ---------------------------------------------------------------------------
// Attention scores (encoder-final only): h·enc_out -> softmax -> w0[b][0..40].
// ---------------------------------------------------------------------------
__device__ __forceinline__ void attn_scores0(int b, int tx,
    const float* __restrict__ hsrc, int hstride,
    const float* __restrict__ enc_out, float* __restrict__ w_out,
    float* h_sh, float* sc_sh)
{
    int wave = tx >> 6, lane = tx & 63;
    h_sh[tx] = hsrc[(size_t)b * hstride + tx];
    __syncthreads();
    const float* eb = enc_out + (size_t)b * NS * NU;
    for (int s = wave; s < NS; s += 16) {
        const float* es = eb + (size_t)s * NU;
        float p = 0.f;
#pragma unroll
        for (int q = 0; q < NU / 64; ++q) p += h_sh[lane + q * 64] * es[lane + q * 64];
#pragma unroll
        for (int off = 32; off > 0; off >>= 1) p += __shfl_down(p, off);
        if (lane == 0) sc_sh[s] = p;
    }
    __syncthreads();
    if (wave == 0) {
        float v = (lane < NS) ? sc_sh[lane] : -3.0e38f;
        float m = v;
#pragma unroll
        for (int off = 32; off > 0; off >>= 1) m = fmaxf(m, __shfl_down(m, off));
        m = __shfl(m, 0);
        float e = (lane < NS) ? expf(v - m) : 0.f;
        float ss = e;
#pragma unroll
        for (int off = 32; off > 0; off >>= 1) ss += __shfl_down(ss, off);
        ss = __shfl(ss, 0);
        if (lane < NS) w_out[(size_t)b * NS + lane] = e / ss;
    }
    __syncthreads();
}

// ---------------------------------------------------------------------------
union SMem {
    float red[4][4][3][256];                  // 48 KB  [kw][mw][g][16x16]
    struct { float h[NU]; float sc[64]; } at;
};

// ---------------------------------------------------------------------------
// Persistent encoder scan (64 blocks x 1024) — unchanged from round 6
// (proven). h state lives in enc_out: sc1-written at t, plain-read (fresh
// first touch) at t+1. t=0: h=0, MFMA skipped.
// ---------------------------------------------------------------------------
__global__ __launch_bounds__(1024) void k_scan_enc(
    const unsigned short* __restrict__ Bp,
    const float* __restrict__ GX, const float* __restrict__ b1,
    float* __restrict__ enc_out,
    float* __restrict__ w0_out,
    unsigned* bar)
{
    __shared__ SMem sm;
    int tx = threadIdx.x;
    int j = blockIdx.x;
    int w = tx >> 6, l = tx & 63;
    int lq = l >> 4, lr = l & 15;
    int mw = w & 3, kw = w >> 2;
    const unsigned short* Bb = Bp + (size_t)j * 96 * 512 + l * 8;
    unsigned ph = 0;

#pragma unroll 1
    for (int t = 0; t < NS; ++t) {
        float4_t acc[3] = {{0,0,0,0},{0,0,0,0},{0,0,0,0}};
        if (t > 0) {
            const float* Ap = enc_out + ((size_t)(mw * 16 + lr) * NS + (t - 1)) * NU
                            + kw * 256 + lq * 8;
#pragma unroll
            for (int sl = 0; sl < 8; ++sl) {
                float4_t f0 = *(const float4_t*)(Ap + sl * 32);
                float4_t f1 = *(const float4_t*)(Ap + sl * 32 + 4);
                short8_t ah, al;
#pragma unroll
                for (int jj = 0; jj < 4; ++jj) {
                    unsigned short h0 = f2bf(f0[jj]);
                    ah[jj] = (short)h0; al[jj] = (short)f2bf(f0[jj] - bf2f(h0));
                    unsigned short h1 = f2bf(f1[jj]);
                    ah[jj + 4] = (short)h1; al[jj + 4] = (short)f2bf(f1[jj] - bf2f(h1));
                }
                int sg = kw * 8 + sl;
#pragma unroll
                for (int g = 0; g < 3; ++g) {
                    const unsigned short* bp = Bb + (size_t)(g * 32 + sg) * 512;
                    short8_t bh = *(const short8_t*)bp;
                    short8_t bl = *(const short8_t*)(bp + PO_S);
                    acc[g] = __builtin_amdgcn_mfma_f32_16x16x32_bf16(ah, bh, acc[g], 0, 0, 0);
                    acc[g] = __builtin_amdgcn_mfma_f32_16x16x32_bf16(ah, bl, acc[g], 0, 0, 0);
                    acc[g] = __builtin_amdgcn_mfma_f32_16x16x32_bf16(al, bh, acc[g], 0, 0, 0);
                }
            }
        }
#pragma unroll
        for (int g = 0; g < 3; ++g)
#pragma unroll
            for (int r = 0; r < 4; ++r)
                sm.red[kw][mw][g][(lq * 4 + r) * 16 + lr] = acc[g][r];
        __syncthreads();

        int b = tx >> 4, c = tx & 15;
        int mw2 = b >> 4, ml = b & 15;
        float gz = 0.f, gr_ = 0.f, gc = 0.f;
#pragma unroll
        for (int k2 = 0; k2 < 4; ++k2) {
            gz  += sm.red[k2][mw2][0][ml * 16 + c];
            gr_ += sm.red[k2][mw2][1][ml * 16 + c];
            gc  += sm.red[k2][mw2][2][ml * 16 + c];
        }
        int col = j * 16 + c;
        const float* gx = GX + ((size_t)b * NS + t) * G3 + col;
        float z = sigmoidf_(gx[0]      + gz  + b1[col]);
        float r = sigmoidf_(gx[NU]     + gr_ + b1[NU + col]);
        float cc = tanhf(gx[2 * NU] + r * (gc + b1[2 * NU + col]));
        float hp = (t > 0) ? enc_out[((size_t)b * NS + (t - 1)) * NU + col] : 0.f;
        float hn = z * hp + (1.f - z) * cc;
        st_coh_f32(enc_out + ((size_t)b * NS + t) * NU + col, hn);

        gsync(bar, ++ph * (unsigned)NB);
    }

    attn_scores0(j, tx, enc_out + (size_t)(NS - 1) * NU, NS * NU,
                 enc_out, w0_out, sm.at.h, sm.at.sc);
}

// ---------------------------------------------------------------------------
// Decoder scan, BARRIER-FREE: the decoder is fully batch-parallel (dec_Wh is
// dead; EG linearized the ctx GEMM), so ONE BLOCK OWNS ONE BATCH and runs all
// 39 steps with only __syncthreads(). No grid barrier, no sc1, no LLC
// round trips. Per step:
//   A: gates[u] = sum_s w[s]*EG[b*40+s][u(+NU,+2NU)] + gx + bias -> h (LDS)
//   B: scores[s] = h . enc_out[b,s,:] -> softmax -> w (LDS)
// EG reads are lane-coalesced (v = tx contiguous); EG[b] = 491 KB L2-resident
// (3.93 MB/XCD). enc_out[b] = 160 KB L2-hot.
// ---------------------------------------------------------------------------
__global__ __launch_bounds__(1024) void k_scan_dec(
    const float* __restrict__ EG,
    const float* __restrict__ GX, const float* __restrict__ b1,
    const float* __restrict__ w0,
    unsigned short* __restrict__ Hs_hi, unsigned short* __restrict__ Hs_lo,
    const float* __restrict__ enc_out)
{
    __shared__ float h_sh[NU];
    __shared__ float w_sh[NS];
    __shared__ float sc_sh[64];
    int tx = threadIdx.x;
    int b = blockIdx.x;
    int wave = tx >> 6, lane = tx & 63;

    if (tx < NS) w_sh[tx] = w0[(size_t)b * NS + tx];
    __syncthreads();

    const float* egb = EG + (size_t)b * NS * G3;
    const float* eb  = enc_out + (size_t)b * NS * NU;

#pragma unroll 1
    for (int t = 0; t < NT; ++t) {
        // ---- phase A: gates + h for col u = tx (block-local) ----
        float ez = 0.f, er = 0.f, ec = 0.f;
#pragma unroll 8
        for (int s = 0; s < NS; ++s) {
            float ws = w_sh[s];
            const float* eg = egb + (size_t)s * G3 + tx;
            ez += ws * eg[0];
            er += ws * eg[NU];
            ec += ws * eg[2 * NU];
        }
        const float* gx = GX + ((size_t)b * NT + t) * G3 + tx;
        float z = sigmoidf_(gx[0]  + ez + b1[tx]);
        float r = sigmoidf_(gx[NU] + er + b1[NU + tx]);
        float cc = tanhf(gx[2 * NU] + ec + r * b1[2 * NU + tx]);
        float hn = (1.f - z) * cc;
        size_t row = (size_t)t * NB + b;
        unsigned short hh = f2bf(hn);
        Hs_hi[row * NU + tx] = hh;
        Hs_lo[row * NU + tx] = f2bf(hn - bf2f(hh));

        if (t < NT - 1) {
            h_sh[tx] = hn;
            __syncthreads();
            // ---- phase B: scores -> softmax -> w (block-local) ----
            for (int s = wave; s < NS; s += 16) {
                const float* es = eb + (size_t)s * NU;
                float p = 0.f;
#pragma unroll
                for (int q = 0; q < NU / 64; ++q)
                    p += h_sh[lane + q * 64] * es[lane + q * 64];
#pragma unroll
                for (int off = 32; off > 0; off >>= 1) p += __shfl_down(p, off);
                if (lane == 0) sc_sh[s] = p;
            }
            __syncthreads();
            if (wave == 0) {
                float v = (lane < NS) ? sc_sh[lane] : -3.0e38f;
                float m = v;
#pragma unroll
                for (int off = 32; off > 0; off >>= 1) m = fmaxf(m, __shfl_down(m, off));
                m = __shfl(m, 0);
                float e = (lane < NS) ? expf(v - m) : 0.f;
                float ss = e;
#pragma unroll
                for (int off = 32; off > 0; off >>= 1) ss += __shfl_down(ss, off);
                ss = __shfl(ss, 0);
                if (lane < NS) w_sh[lane] = e / ss;
            }
            __syncthreads();
        }
    }
}

// ---------------------------------------------------------------------------
// FC: 1280 blocks, XCD-aware remap; hi/lo weight planes in separate buffers.
// ---------------------------------------------------------------------------
__global__ __launch_bounds__(256) void k_fc_mfma(const unsigned short* __restrict__ Ah,
                                                 const unsigned short* __restrict__ Al,
                                                 const unsigned short* __restrict__ Bh,
                                                 const unsigned short* __restrict__ Bl,
                                                 const float* __restrict__ bias,
                                                 float* __restrict__ out)
{
    int tx = threadIdx.x;
    int w = tx >> 6, l = tx & 63;
    int lq = l >> 4, lr = l & 15;
    int lin = blockIdx.x + blockIdx.y * gridDim.x;
    int xcd = lin & 7;
    int slot = lin >> 3;
    int cb = (xcd << 4) | (slot & 15);
    int row0 = (slot >> 4) * 256 + w * 64;
    float4_t acc[4][4];
#pragma unroll
    for (int i = 0; i < 4; ++i)
#pragma unroll
        for (int jn = 0; jn < 4; ++jn) acc[i][jn] = (float4_t){0.f, 0.f, 0.f, 0.f};
#pragma unroll 1
    for (int s = 0; s < NU / 32; ++s) {
        short8_t ah[4], al[4];
#pragma unroll
        for (int mf = 0; mf < 4; ++mf) {
            const unsigned short* ap = Ah + (size_t)(row0 + mf * 16 + lr) * NU + s * 32 + lq * 8;
            const unsigned short* alp = Al + (size_t)(row0 + mf * 16 + lr) * NU + s * 32 + lq * 8;
            ah[mf] = *(const short8_t*)ap;
            al[mf] = *(const short8_t*)alp;
        }
#pragma unroll
        for (int nf = 0; nf < 4; ++nf) {
            size_t idx = ((((size_t)cb * 4 + nf) * 32 + s) * 64 + l) * 8;
            short8_t bh = *(const short8_t*)(Bh + idx);
            short8_t bl = *(const short8_t*)(Bl + idx);
#pragma unroll
            for (int mf = 0; mf < 4; ++mf) {
                acc[mf][nf] = __builtin_amdgcn_mfma_f32_16x16x32_bf16(ah[mf], bh, acc[mf][nf], 0, 0, 0);
                acc[mf][nf] = __builtin_amdgcn_mfma_f32_16x16x32_bf16(ah[mf], bl, acc[mf][nf], 0, 0, 0);
                acc[mf][nf] = __builtin_amdgcn_mfma_f32_16x16x32_bf16(al[mf], bh, acc[mf][nf], 0, 0, 0);
            }
        }
    }
#pragma unroll
    for (int nf = 0; nf < 4; ++nf) {
        int v = cb * 64 + nf * 16 + lr;
        float bi = bias[v];
#pragma unroll
        for (int mf = 0; mf < 4; ++mf)
#pragma unroll
            for (int r = 0; r < 4; ++r) {
                int gr = row0 + mf * 16 + lq * 4 + r;   // Hs row = t*64 + b
                if (gr < NT * NB) {
                    int tt = gr >> 6, bb = gr & 63;
                    out[((size_t)bb * NT + tt) * NVO + v] = acc[mf][nf][r] + bi;
                }
            }
    }
}

// ---------------------------------------------------------------------------

extern "C" void kernel_launch(void* const* d_in, const int* in_sizes, int n_in,
                              void* d_out, int out_size, void* d_ws, size_t ws_size,
                              hipStream_t stream)
{
    const int*   inp     = (const int*)d_in[0];
    const int*   targ    = (const int*)d_in[1];
    const float* enc_emb = (const float*)d_in[2];
    const float* enc_Wx  = (const float*)d_in[3];
    const float* enc_Wh  = (const float*)d_in[4];
    const float* enc_b   = (const float*)d_in[5];
    const float* dec_emb = (const float*)d_in[6];
    const float* dec_Wx  = (const float*)d_in[7];
    // d_in[8] = dec_Wh: unused (multiplied by h_zero == 0 in reference)
    const float* dec_b   = (const float*)d_in[9];
    const float* fc_W    = (const float*)d_in[10];
    const float* fc_b    = (const float*)d_in[11];
    float* out = (float*)d_out;

    // ---- workspace carve: identical to proven round-6 layout (84.56 MB) ----
    char* p = (char*)d_ws;
    // R1 (31,457,280): gx_buf (enc, then dec) -> Bp_fc HI plane after dec scan
    float*          gx_buf = (float*)p;
    unsigned short* BfcH   = (unsigned short*)p;
    p += 31457280;
    // R2 (10,485,760): enc_out fp32 [b][s][u]
    float* enc_out = (float*)p;  p += 10485760;
    // R3 (10,485,760): Bp_egw single plane (6.29 MB, eg passes) -> Hs hi/lo
    unsigned short* Bp_egw = (unsigned short*)p;
    unsigned short* Hs_hi  = (unsigned short*)p;
    unsigned short* Hs_lo  = Hs_hi + 2621440;   // +5,242,880 B
    p += 10485760;
    // R4 (31,457,280): [Bp_wh 12.58 | Ax 1.31 | Bp_gx 3.15] -> EG -> Bp_fc LO
    char* r4 = p;
    unsigned short* Bp_wh = (unsigned short*)r4;
    unsigned short* Ax    = (unsigned short*)(r4 + 12582912);
    unsigned short* Bp_gx = (unsigned short*)(r4 + 13893632);
    float*          EG    = (float*)r4;          // [rb=b*40+s][G3] fp32
    unsigned short* BfcL  = (unsigned short*)r4;
    p += 31457280;
    // R5: w0 + (reserved) + barrier counters
    float* w0_buf  = (float*)p; p += 409600;
    p += 262144;                                 // reserved (was hdec)
    unsigned* bars = (unsigned*)p; p += 256;

    hipMemsetAsync(bars, 0, 256, stream);

    // pack encoder recurrent weights
    k_pack_step<<<dim3(64, 96), 64, 0, stream>>>(enc_Wh, Bp_wh);

    // ---- encoder x-path ----
    k_pack_b<<<dim3(G3 / 16, NE / 32), 64, 0, stream>>>(enc_Wx, G3, Bp_gx, PO_GX);
    k_gather<<<NB * NS, NE, 0, stream>>>(inp, NS, NS, enc_emb, Ax);
    k_gx_mfma<<<dim3(NB * NS / 64, 48), 256, 0, stream>>>(Ax, Bp_gx, enc_b, gx_buf);

    // ---- encoder scan: ONE persistent kernel (40 steps + w0) ----
    k_scan_enc<<<64, 1024, 0, stream>>>(Bp_wh, gx_buf, enc_b + G3,
                                        enc_out, w0_buf, bars);

    // ---- decoder x-path ----
    k_pack_b<<<dim3(G3 / 16, NE / 32), 64, 0, stream>>>(dec_Wx + (size_t)NU * G3, G3, Bp_gx, PO_GX);
    k_gather<<<NB * NT, NE, 0, stream>>>(targ, NS, NT, dec_emb, Ax);
    k_gx_mfma<<<dim3(NB * NT / 64, 48), 256, 0, stream>>>(Ax, Bp_gx, dec_b, gx_buf);

    // ---- EG precompute (two passes; clobbers Bp_wh/Ax/Bp_gx: all dead) ----
    k_pack_b1<<<dim3(G3 / 16, NU / 32), 64, 0, stream>>>(dec_Wx, G3, Bp_egw, 0);
    k_eg_mfma<0><<<dim3(NB * NS / 64, 48), 256, 0, stream>>>(enc_out, Bp_egw, EG);
    k_pack_b1<<<dim3(G3 / 16, NU / 32), 64, 0, stream>>>(dec_Wx, G3, Bp_egw, 1);
    k_eg_mfma<1><<<dim3(NB * NS / 64, 48), 256, 0, stream>>>(enc_out, Bp_egw, EG);

    // ---- decoder scan: 64 independent blocks, one batch each, NO barriers ----
    k_scan_dec<<<64, 1024, 0, stream>>>(EG, gx_buf, dec_b + G3, w0_buf,
                                        Hs_hi, Hs_lo, enc_out);

    // ---- FC head (hi plane over gx region, lo plane over EG region) ----
    k_pack_b2<<<dim3(NVO / 16, NU / 32), 64, 0, stream>>>(fc_W, NVO, BfcH, BfcL);
    k_fc_mfma<<<dim3(10, NVO / 64), 256, 0, stream>>>(Hs_hi, Hs_lo, BfcH, BfcL, fc_b, out);
}

// Round 8
// 1389.407 us; speedup vs baseline: 2.7918x; 1.2801x over previous
//
#include <hip/hip_runtime.h>
#include <hip/hip_bf16.h>

#define NB 64      // batch
#define NS 40      // src len
#define NT 39      // tgt steps (T-1)
#define NE 256     // emb
#define NU 1024    // hidden
#define G3 3072    // 3*U
#define NVO 8192

typedef __attribute__((ext_vector_type(8))) short short8_t;   // 8 x bf16 frag
typedef __attribute__((ext_vector_type(4))) float float4_t;   // 4 x f32 acc

// ushort plane offsets inside two-plane packs
#define PO_S  3145728   // Bp_wh: 64 blk * 96 * 64 * 8
#define PO_GX 786432    // Bp_gx: 192 * 8 * 64 * 8

// ---------------------------------------------------------------------------
__device__ __forceinline__ unsigned short f2bf(float x) {
    union { float f; unsigned u; } v; v.f = x;
    unsigned r = v.u + 0x7fffu + ((v.u >> 16) & 1u);
    return (unsigned short)(r >> 16);
}
__device__ __forceinline__ float bf2f(unsigned short h) {
    union { float f; unsigned u; } v; v.u = ((unsigned)h) << 16; return v.f;
}
__device__ __forceinline__ float sigmoidf_(float x) { return 1.0f / (1.0f + expf(-x)); }

// ---------------------------------------------------------------------------
// Agent-scope helpers (rounds 4/6/7 proven): sc1 ops bypass per-XCD L2, hit
// the LLC (coherence point). Encoder scan only.
// ---------------------------------------------------------------------------
__device__ __forceinline__ float ld_coh_f32(const float* p) {
    return __hip_atomic_load((float*)p, __ATOMIC_RELAXED, __HIP_MEMORY_SCOPE_AGENT);
}
__device__ __forceinline__ void st_coh_f32(float* p, float v) {
    __hip_atomic_store(p, v, __ATOMIC_RELAXED, __HIP_MEMORY_SCOPE_AGENT);
}

// ---------------------------------------------------------------------------
// Software grid barrier, fence-free (rounds 4/6/7 proven). s_sleep(4) this
// round: 256 pollers on one LLC line, longer naps cut poll contention.
// ---------------------------------------------------------------------------
__device__ __forceinline__ void gsync(unsigned* bar, unsigned goal)
{
    __syncthreads();
    if (threadIdx.x == 0) {
        __hip_atomic_fetch_add(bar, 1u, __ATOMIC_RELAXED, __HIP_MEMORY_SCOPE_AGENT);
        int spin = 0;
        while (__hip_atomic_load(bar, __ATOMIC_RELAXED, __HIP_MEMORY_SCOPE_AGENT) < goal
               && spin < 8192) {
            __builtin_amdgcn_s_sleep(4);
            ++spin;
        }
        asm volatile("" ::: "memory");
    }
    __syncthreads();
}

// ---------------------------------------------------------------------------
// Packers (unchanged, round-7 proven).
// ---------------------------------------------------------------------------
__global__ __launch_bounds__(64) void k_pack_b(const float* __restrict__ W, int N,
                                               unsigned short* __restrict__ Bp, int planeOff)
{
    int nt = blockIdx.x, s = blockIdx.y;
    int l = threadIdx.x;
    int n = nt * 16 + (l & 15);
    int k0 = s * 32 + (l >> 4) * 8;
    size_t ob = (((size_t)nt * gridDim.y + s) * 64 + l) * 8;
#pragma unroll
    for (int jj = 0; jj < 8; ++jj) {
        float x = W[(size_t)(k0 + jj) * N + n];
        unsigned short h = f2bf(x);
        Bp[ob + jj] = h;
        Bp[planeOff + ob + jj] = f2bf(x - bf2f(h));
    }
}

__global__ __launch_bounds__(64) void k_pack_b1(const float* __restrict__ W, int N,
                                                unsigned short* __restrict__ Bp, int plane)
{
    int nt = blockIdx.x, s = blockIdx.y;
    int l = threadIdx.x;
    int n = nt * 16 + (l & 15);
    int k0 = s * 32 + (l >> 4) * 8;
    size_t ob = (((size_t)nt * gridDim.y + s) * 64 + l) * 8;
#pragma unroll
    for (int jj = 0; jj < 8; ++jj) {
        float x = W[(size_t)(k0 + jj) * N + n];
        unsigned short h = f2bf(x);
        Bp[ob + jj] = plane ? f2bf(x - bf2f(h)) : h;
    }
}

__global__ __launch_bounds__(64) void k_pack_b2(const float* __restrict__ W, int N,
                                                unsigned short* __restrict__ Bh,
                                                unsigned short* __restrict__ Bl)
{
    int nt = blockIdx.x, s = blockIdx.y;
    int l = threadIdx.x;
    int n = nt * 16 + (l & 15);
    int k0 = s * 32 + (l >> 4) * 8;
    size_t ob = (((size_t)nt * gridDim.y + s) * 64 + l) * 8;
#pragma unroll
    for (int jj = 0; jj < 8; ++jj) {
        float x = W[(size_t)(k0 + jj) * N + n];
        unsigned short h = f2bf(x);
        Bh[ob + jj] = h;
        Bl[ob + jj] = f2bf(x - bf2f(h));
    }
}

__global__ __launch_bounds__(64) void k_pack_step(const float* __restrict__ W,
                                                  unsigned short* __restrict__ Bp)
{
    int j = blockIdx.x;
    int q = blockIdx.y;            // g*32 + s
    int g = q >> 5, s = q & 31;
    int l = threadIdx.x;
    int n = g * NU + j * 16 + (l & 15);
    int k0 = s * 32 + (l >> 4) * 8;
    size_t ob = (((size_t)j * 96 + q) * 64 + l) * 8;
#pragma unroll
    for (int jj = 0; jj < 8; ++jj) {
        float x = W[(size_t)(k0 + jj) * G3 + n];
        unsigned short h = f2bf(x);
        Bp[ob + jj] = h;
        Bp[PO_S + ob + jj] = f2bf(x - bf2f(h));
    }
}

__global__ __launch_bounds__(256) void k_gather(const int* __restrict__ idx,
                                                int cols_total, int cols_used,
                                                const float* __restrict__ emb,
                                                unsigned short* __restrict__ Ax)
{
    int row = blockIdx.x;
    int b = row / cols_used, c = row - b * cols_used;
    int tok = idx[b * cols_total + c];
    int k = threadIdx.x;
    Ax[(size_t)row * NE + k] = f2bf(emb[(size_t)tok * NE + k]);
}

// GX GEMM (unchanged).
__global__ __launch_bounds__(256) void k_gx_mfma(const unsigned short* __restrict__ Ax,
                                                 const unsigned short* __restrict__ Bp,
                                                 const float* __restrict__ bias,
                                                 float* __restrict__ out)
{
    int tx = threadIdx.x;
    int w = tx >> 6, l = tx & 63;
    int lq = l >> 4, lr = l & 15;
    int row0 = blockIdx.x * 64 + w * 16;
    int cb = blockIdx.y;
    float4_t acc[4] = {{0,0,0,0},{0,0,0,0},{0,0,0,0},{0,0,0,0}};
    const unsigned short* Ab = Ax + (size_t)(row0 + lr) * NE + lq * 8;
#pragma unroll
    for (int s = 0; s < 8; ++s) {
        short8_t ah = *(const short8_t*)(Ab + s * 32);
#pragma unroll
        for (int nf = 0; nf < 4; ++nf) {
            const unsigned short* bp = Bp + ((((size_t)cb * 4 + nf) * 8 + s) * 64 + l) * 8;
            short8_t bh = *(const short8_t*)bp;
            short8_t bl = *(const short8_t*)(bp + PO_GX);
            acc[nf] = __builtin_amdgcn_mfma_f32_16x16x32_bf16(ah, bh, acc[nf], 0, 0, 0);
            acc[nf] = __builtin_amdgcn_mfma_f32_16x16x32_bf16(ah, bl, acc[nf], 0, 0, 0);
        }
    }
#pragma unroll
    for (int nf = 0; nf < 4; ++nf) {
        int col = cb * 64 + nf * 16 + lr;
        float bi = bias[col];
#pragma unroll
        for (int r = 0; r < 4; ++r) {
            int gr = row0 + lq * 4 + r;
            out[(size_t)gr * G3 + col] = acc[nf][r] + bi;
        }
    }
}

// ---------------------------------------------------------------------------
// EG GEMM (unchanged, round-7 proven).
// ---------------------------------------------------------------------------
template<int PASS>
__global__ __launch_bounds__(256) void k_eg_mfma(const float* __restrict__ enc_out,
                                                 const unsigned short* __restrict__ Bp,
                                                 float* __restrict__ EG)
{
    int tx = threadIdx.x;
    int w = tx >> 6, l = tx & 63;
    int lq = l >> 4, lr = l & 15;
    int row0 = blockIdx.x * 64 + w * 16;
    int cb = blockIdx.y;
    float4_t acc[4] = {{0,0,0,0},{0,0,0,0},{0,0,0,0},{0,0,0,0}};
    const float* Ab = enc_out + (size_t)(row0 + lr) * NU + lq * 8;
#pragma unroll 1
    for (int s = 0; s < NU / 32; ++s) {
        float4_t f0 = *(const float4_t*)(Ab + s * 32);
        float4_t f1 = *(const float4_t*)(Ab + s * 32 + 4);
        short8_t ah, al;
#pragma unroll
        for (int jj = 0; jj < 4; ++jj) {
            unsigned short h0 = f2bf(f0[jj]);
            ah[jj] = (short)h0; al[jj] = (short)f2bf(f0[jj] - bf2f(h0));
            unsigned short h1 = f2bf(f1[jj]);
            ah[jj + 4] = (short)h1; al[jj + 4] = (short)f2bf(f1[jj] - bf2f(h1));
        }
#pragma unroll
        for (int nf = 0; nf < 4; ++nf) {
            const unsigned short* bp = Bp + ((((size_t)cb * 4 + nf) * 32 + s) * 64 + l) * 8;
            short8_t bv = *(const short8_t*)bp;
            acc[nf] = __builtin_amdgcn_mfma_f32_16x16x32_bf16(ah, bv, acc[nf], 0, 0, 0);
            if (PASS == 0)
                acc[nf] = __builtin_amdgcn_mfma_f32_16x16x32_bf16(al, bv, acc[nf], 0, 0, 0);
        }
    }
#pragma unroll
    for (int nf = 0; nf < 4; ++nf) {
        int v = cb * 64 + nf * 16 + lr;
#pragma unroll
        for (int r = 0; r < 4; ++r) {
            int gr = row0 + lq * 4 + r;          // rb = b*40 + s
            size_t o = (size_t)gr * G3 + v;
            if (PASS == 0) EG[o] = acc[nf][r];
            else           EG[o] += acc[nf][r];
        }
    }
}

// ---------------------------------------------------------------------------
// Attention scores (encoder-final only): h·enc_out -> softmax -> w0.
// ---------------------------------------------------------------------------
__device__ __forceinline__ void attn_scores0(int b, int tx,
    const float* __restrict__ hsrc, int hstride,
    const float* __restrict__ enc_out, float* __restrict__ w_out,
    float* h_sh, float* sc_sh)
{
    int wave = tx >> 6, lane = tx & 63;
    h_sh[tx] = hsrc[(size_t)b * hstride + tx];
    __syncthreads();
    const float* eb = enc_out + (size_t)b * NS * NU;
    for (int s = wave; s < NS; s += 16) {
        const float* es = eb + (size_t)s * NU;
        float p = 0.f;
#pragma unroll
        for (int q = 0; q < NU / 64; ++q) p += h_sh[lane + q * 64] * es[lane + q * 64];
#pragma unroll
        for (int off = 32; off > 0; off >>= 1) p += __shfl_down(p, off);
        if (lane == 0) sc_sh[s] = p;
    }
    __syncthreads();
    if (wave == 0) {
        float v = (lane < NS) ? sc_sh[lane] : -3.0e38f;
        float m = v;
#pragma unroll
        for (int off = 32; off > 0; off >>= 1) m = fmaxf(m, __shfl_down(m, off));
        m = __shfl(m, 0);
        float e = (lane < NS) ? expf(v - m) : 0.f;
        float ss = e;
#pragma unroll
        for (int off = 32; off > 0; off >>= 1) ss += __shfl_down(ss, off);
        ss = __shfl(ss, 0);
        if (lane < NS) w_out[(size_t)b * NS + lane] = e / ss;
    }
    __syncthreads();
}

// ---------------------------------------------------------------------------
// Encoder scan LDS overlay: 16-way K-split partials, or attn buffers.
// ---------------------------------------------------------------------------
union SMemE {
    float red[16][3][256];                    // 48 KB [kw][g][16x16]
    struct { float h[NU]; float sc[64]; } at;
};

// ---------------------------------------------------------------------------
// Persistent encoder scan, 256-BLOCK M-SPLIT: block lin -> (xcd=lin&7,
// mb=(lin>>3)&3, jhi=lin>>5), j = xcd*8+jhi. Block computes gate cols
// 16j..16j+16 for batches 16mb..16mb+16 — 4x the round-7 parallelism, so
// the per-step compute term (MFMA + f2bf) quarters. XCD-aware j split keeps
// each XCD's weight working set at 8 panels = 1.57 MB (L2-resident).
// 16 waves = 16-way K-split (64 K-cols each); LDS 16-way reduce; 256-thread
// epilogue with gx/h_prev PREFETCHED at phase start (LLC latency hides under
// MFMA instead of serializing after the reduce).
// h handoff unchanged (round-7 proven): sc1-write enc_out[:,t,:], plain
// fresh-read at t+1.
// ---------------------------------------------------------------------------
__global__ __launch_bounds__(1024) void k_scan_enc(
    const unsigned short* __restrict__ Bp,
    const float* __restrict__ GX, const float* __restrict__ b1,
    float* __restrict__ enc_out,
    float* __restrict__ w0_out,
    unsigned* bar)
{
    __shared__ SMemE sm;
    int tx = threadIdx.x;
    int lin = blockIdx.x;
    int xcd = lin & 7, mb = (lin >> 3) & 3, jhi = lin >> 5;
    int j = xcd * 8 + jhi;
    int w = tx >> 6, l = tx & 63;
    int lq = l >> 4, lr = l & 15;
    int kw = w;                                  // 16 K-chunks of 64 cols
    const unsigned short* Bb = Bp + (size_t)j * 96 * 512 + l * 8;
    // epilogue mapping (tx < 256)
    int bl = tx >> 4, c = tx & 15;
    int col = j * 16 + c;
    int b = mb * 16 + bl;
    unsigned ph = 0;

#pragma unroll 1
    for (int t = 0; t < NS; ++t) {
        // prefetch epilogue operands (independent of this step's MFMA)
        float gx0 = 0.f, gx1 = 0.f, gx2 = 0.f, hp = 0.f;
        if (tx < 256) {
            const float* gx = GX + ((size_t)b * NS + t) * G3 + col;
            gx0 = gx[0]; gx1 = gx[NU]; gx2 = gx[2 * NU];
            if (t > 0) hp = enc_out[((size_t)b * NS + (t - 1)) * NU + col];
        }

        float4_t acc[3] = {{0,0,0,0},{0,0,0,0},{0,0,0,0}};
        if (t > 0) {
            const float* Ap = enc_out + ((size_t)(mb * 16 + lr) * NS + (t - 1)) * NU
                            + kw * 64 + lq * 8;
#pragma unroll
            for (int sl = 0; sl < 2; ++sl) {
                float4_t f0 = *(const float4_t*)(Ap + sl * 32);
                float4_t f1 = *(const float4_t*)(Ap + sl * 32 + 4);
                short8_t ah, al;
#pragma unroll
                for (int jj = 0; jj < 4; ++jj) {
                    unsigned short h0 = f2bf(f0[jj]);
                    ah[jj] = (short)h0; al[jj] = (short)f2bf(f0[jj] - bf2f(h0));
                    unsigned short h1 = f2bf(f1[jj]);
                    ah[jj + 4] = (short)h1; al[jj + 4] = (short)f2bf(f1[jj] - bf2f(h1));
                }
                int sg = kw * 2 + sl;
#pragma unroll
                for (int g = 0; g < 3; ++g) {
                    const unsigned short* bp = Bb + (size_t)(g * 32 + sg) * 512;
                    short8_t bh = *(const short8_t*)bp;
                    short8_t bv = *(const short8_t*)(bp + PO_S);
                    acc[g] = __builtin_amdgcn_mfma_f32_16x16x32_bf16(ah, bh, acc[g], 0, 0, 0);
                    acc[g] = __builtin_amdgcn_mfma_f32_16x16x32_bf16(ah, bv, acc[g], 0, 0, 0);
                    acc[g] = __builtin_amdgcn_mfma_f32_16x16x32_bf16(al, bh, acc[g], 0, 0, 0);
                }
            }
        }
#pragma unroll
        for (int g = 0; g < 3; ++g)
#pragma unroll
            for (int r = 0; r < 4; ++r)
                sm.red[kw][g][(lq * 4 + r) * 16 + lr] = acc[g][r];
        __syncthreads();

        if (tx < 256) {
            float gz = 0.f, gr_ = 0.f, gc = 0.f;
#pragma unroll
            for (int k2 = 0; k2 < 16; ++k2) {
                gz  += sm.red[k2][0][bl * 16 + c];
                gr_ += sm.red[k2][1][bl * 16 + c];
                gc  += sm.red[k2][2][bl * 16 + c];
            }
            float z = sigmoidf_(gx0 + gz  + b1[col]);
            float r = sigmoidf_(gx1 + gr_ + b1[NU + col]);
            float cc = tanhf(gx2 + r * (gc + b1[2 * NU + col]));
            float hn = z * hp + (1.f - z) * cc;
            st_coh_f32(enc_out + ((size_t)b * NS + t) * NU + col, hn);
        }

        gsync(bar, ++ph * 256u);
    }

    // initial decoder attention weights -> w0 (64 blocks, one batch each)
    if (lin < NB)
        attn_scores0(lin, tx, enc_out + (size_t)(NS - 1) * NU, NS * NU,
                     enc_out, w0_out, sm.at.h, sm.at.sc);
}

// ---------------------------------------------------------------------------
// Decoder scan, BARRIER-FREE (round-7 proven, unchanged): one block owns one
// batch; EG linearization; only __syncthreads().
// ---------------------------------------------------------------------------
__global__ __launch_bounds__(1024) void k_scan_dec(
    const float* __restrict__ EG,
    const float* __restrict__ GX, const float* __restrict__ b1,
    const float* __restrict__ w0,
    unsigned short* __restrict__ Hs_hi, unsigned short* __restrict__ Hs_lo,
    const float* __restrict__ enc_out)
{
    __shared__ float h_sh[NU];
    __shared__ float w_sh[NS];
    __shared__ float sc_sh[64];
    int tx = threadIdx.x;
    int b = blockIdx.x;
    int wave = tx >> 6, lane = tx & 63;

    if (tx < NS) w_sh[tx] = w0[(size_t)b * NS + tx];
    __syncthreads();

    const float* egb = EG + (size_t)b * NS * G3;
    const float* eb  = enc_out + (size_t)b * NS * NU;

#pragma unroll 1
    for (int t = 0; t < NT; ++t) {
        float ez = 0.f, er = 0.f, ec = 0.f;
#pragma unroll 8
        for (int s = 0; s < NS; ++s) {
            float ws = w_sh[s];
            const float* eg = egb + (size_t)s * G3 + tx;
            ez += ws * eg[0];
            er += ws * eg[NU];
            ec += ws * eg[2 * NU];
        }
        const float* gx = GX + ((size_t)b * NT + t) * G3 + tx;
        float z = sigmoidf_(gx[0]  + ez + b1[tx]);
        float r = sigmoidf_(gx[NU] + er + b1[NU + tx]);
        float cc = tanhf(gx[2 * NU] + ec + r * b1[2 * NU + tx]);
        float hn = (1.f - z) * cc;
        size_t row = (size_t)t * NB + b;
        unsigned short hh = f2bf(hn);
        Hs_hi[row * NU + tx] = hh;
        Hs_lo[row * NU + tx] = f2bf(hn - bf2f(hh));

        if (t < NT - 1) {
            h_sh[tx] = hn;
            __syncthreads();
            for (int s = wave; s < NS; s += 16) {
                const float* es = eb + (size_t)s * NU;
                float p = 0.f;
#pragma unroll
                for (int q = 0; q < NU / 64; ++q)
                    p += h_sh[lane + q * 64] * es[lane + q * 64];
#pragma unroll
                for (int off = 32; off > 0; off >>= 1) p += __shfl_down(p, off);
                if (lane == 0) sc_sh[s] = p;
            }
            __syncthreads();
            if (wave == 0) {
                float v = (lane < NS) ? sc_sh[lane] : -3.0e38f;
                float m = v;
#pragma unroll
                for (int off = 32; off > 0; off >>= 1) m = fmaxf(m, __shfl_down(m, off));
                m = __shfl(m, 0);
                float e = (lane < NS) ? expf(v - m) : 0.f;
                float ss = e;
#pragma unroll
                for (int off = 32; off > 0; off >>= 1) ss += __shfl_down(ss, off);
                ss = __shfl(ss, 0);
                if (lane < NS) w_sh[lane] = e / ss;
            }
            __syncthreads();
        }
    }
}

// ---------------------------------------------------------------------------
// FC (unchanged, round-7 proven).
// ---------------------------------------------------------------------------
__global__ __launch_bounds__(256) void k_fc_mfma(const unsigned short* __restrict__ Ah,
                                                 const unsigned short* __restrict__ Al,
                                                 const unsigned short* __restrict__ Bh,
                                                 const unsigned short* __restrict__ Bl,
                                                 const float* __restrict__ bias,
                                                 float* __restrict__ out)
{
    int tx = threadIdx.x;
    int w = tx >> 6, l = tx & 63;
    int lq = l >> 4, lr = l & 15;
    int lin = blockIdx.x + blockIdx.y * gridDim.x;
    int xcd = lin & 7;
    int slot = lin >> 3;
    int cb = (xcd << 4) | (slot & 15);
    int row0 = (slot >> 4) * 256 + w * 64;
    float4_t acc[4][4];
#pragma unroll
    for (int i = 0; i < 4; ++i)
#pragma unroll
        for (int jn = 0; jn < 4; ++jn) acc[i][jn] = (float4_t){0.f, 0.f, 0.f, 0.f};
#pragma unroll 1
    for (int s = 0; s < NU / 32; ++s) {
        short8_t ah[4], al[4];
#pragma unroll
        for (int mf = 0; mf < 4; ++mf) {
            const unsigned short* ap = Ah + (size_t)(row0 + mf * 16 + lr) * NU + s * 32 + lq * 8;
            const unsigned short* alp = Al + (size_t)(row0 + mf * 16 + lr) * NU + s * 32 + lq * 8;
            ah[mf] = *(const short8_t*)ap;
            al[mf] = *(const short8_t*)alp;
        }
#pragma unroll
        for (int nf = 0; nf < 4; ++nf) {
            size_t idx = ((((size_t)cb * 4 + nf) * 32 + s) * 64 + l) * 8;
            short8_t bh = *(const short8_t*)(Bh + idx);
            short8_t bl = *(const short8_t*)(Bl + idx);
#pragma unroll
            for (int mf = 0; mf < 4; ++mf) {
                acc[mf][nf] = __builtin_amdgcn_mfma_f32_16x16x32_bf16(ah[mf], bh, acc[mf][nf], 0, 0, 0);
                acc[mf][nf] = __builtin_amdgcn_mfma_f32_16x16x32_bf16(ah[mf], bl, acc[mf][nf], 0, 0, 0);
                acc[mf][nf] = __builtin_amdgcn_mfma_f32_16x16x32_bf16(al[mf], bh, acc[mf][nf], 0, 0, 0);
            }
        }
    }
#pragma unroll
    for (int nf = 0; nf < 4; ++nf) {
        int v = cb * 64 + nf * 16 + lr;
        float bi = bias[v];
#pragma unroll
        for (int mf = 0; mf < 4; ++mf)
#pragma unroll
            for (int r = 0; r < 4; ++r) {
                int gr = row0 + mf * 16 + lq * 4 + r;   // Hs row = t*64 + b
                if (gr < NT * NB) {
                    int tt = gr >> 6, bb = gr & 63;
                    out[((size_t)bb * NT + tt) * NVO + v] = acc[mf][nf][r] + bi;
                }
            }
    }
}

// ---------------------------------------------------------------------------

extern "C" void kernel_launch(void* const* d_in, const int* in_sizes, int n_in,
                              void* d_out, int out_size, void* d_ws, size_t ws_size,
                              hipStream_t stream)
{
    const int*   inp     = (const int*)d_in[0];
    const int*   targ    = (const int*)d_in[1];
    const float* enc_emb = (const float*)d_in[2];
    const float* enc_Wx  = (const float*)d_in[3];
    const float* enc_Wh  = (const float*)d_in[4];
    const float* enc_b   = (const float*)d_in[5];
    const float* dec_emb = (const float*)d_in[6];
    const float* dec_Wx  = (const float*)d_in[7];
    // d_in[8] = dec_Wh: unused (multiplied by h_zero == 0 in reference)
    const float* dec_b   = (const float*)d_in[9];
    const float* fc_W    = (const float*)d_in[10];
    const float* fc_b    = (const float*)d_in[11];
    float* out = (float*)d_out;

    // ---- workspace carve: identical to proven round-6/7 layout (84.56 MB) ----
    char* p = (char*)d_ws;
    // R1 (31,457,280): gx_buf (enc, then dec) -> Bp_fc HI plane after dec scan
    float*          gx_buf = (float*)p;
    unsigned short* BfcH   = (unsigned short*)p;
    p += 31457280;
    // R2 (10,485,760): enc_out fp32 [b][s][u]
    float* enc_out = (float*)p;  p += 10485760;
    // R3 (10,485,760): Bp_egw single plane (6.29 MB, eg passes) -> Hs hi/lo
    unsigned short* Bp_egw = (unsigned short*)p;
    unsigned short* Hs_hi  = (unsigned short*)p;
    unsigned short* Hs_lo  = Hs_hi + 2621440;   // +5,242,880 B
    p += 10485760;
    // R4 (31,457,280): [Bp_wh 12.58 | Ax 1.31 | Bp_gx 3.15] -> EG -> Bp_fc LO
    char* r4 = p;
    unsigned short* Bp_wh = (unsigned short*)r4;
    unsigned short* Ax    = (unsigned short*)(r4 + 12582912);
    unsigned short* Bp_gx = (unsigned short*)(r4 + 13893632);
    float*          EG    = (float*)r4;          // [rb=b*40+s][G3] fp32
    unsigned short* BfcL  = (unsigned short*)r4;
    p += 31457280;
    // R5: w0 + (reserved) + barrier counters
    float* w0_buf  = (float*)p; p += 409600;
    p += 262144;                                 // reserved
    unsigned* bars = (unsigned*)p; p += 256;

    hipMemsetAsync(bars, 0, 256, stream);

    // pack encoder recurrent weights
    k_pack_step<<<dim3(64, 96), 64, 0, stream>>>(enc_Wh, Bp_wh);

    // ---- encoder x-path ----
    k_pack_b<<<dim3(G3 / 16, NE / 32), 64, 0, stream>>>(enc_Wx, G3, Bp_gx, PO_GX);
    k_gather<<<NB * NS, NE, 0, stream>>>(inp, NS, NS, enc_emb, Ax);
    k_gx_mfma<<<dim3(NB * NS / 64, 48), 256, 0, stream>>>(Ax, Bp_gx, enc_b, gx_buf);

    // ---- encoder scan: ONE persistent kernel, 256-block M-split ----
    k_scan_enc<<<256, 1024, 0, stream>>>(Bp_wh, gx_buf, enc_b + G3,
                                         enc_out, w0_buf, bars);

    // ---- decoder x-path ----
    k_pack_b<<<dim3(G3 / 16, NE / 32), 64, 0, stream>>>(dec_Wx + (size_t)NU * G3, G3, Bp_gx, PO_GX);
    k_gather<<<NB * NT, NE, 0, stream>>>(targ, NS, NT, dec_emb, Ax);
    k_gx_mfma<<<dim3(NB * NT / 64, 48), 256, 0, stream>>>(Ax, Bp_gx, dec_b, gx_buf);

    // ---- EG precompute (two passes; clobbers Bp_wh/Ax/Bp_gx: all dead) ----
    k_pack_b1<<<dim3(G3 / 16, NU / 32), 64, 0, stream>>>(dec_Wx, G3, Bp_egw, 0);
    k_eg_mfma<0><<<dim3(NB * NS / 64, 48), 256, 0, stream>>>(enc_out, Bp_egw, EG);
    k_pack_b1<<<dim3(G3 / 16, NU / 32), 64, 0, stream>>>(dec_Wx, G3, Bp_egw, 1);
    k_eg_mfma<1><<<dim3(NB * NS / 64, 48), 256, 0, stream>>>(enc_out, Bp_egw, EG);

    // ---- decoder scan: 64 independent blocks, one batch each, NO barriers ----
    k_scan_dec<<<64, 1024, 0, stream>>>(EG, gx_buf, dec_b + G3, w0_buf,
                                        Hs_hi, Hs_lo, enc_out);

    // ---- FC head ----
    k_pack_b2<<<dim3(NVO / 16, NU / 32), 64, 0, stream>>>(fc_W, NVO, BfcH, BfcL);
    k_fc_mfma<<<dim3(10, NVO / 64), 256, 0, stream>>>(Hs_hi, Hs_lo, BfcH, BfcL, fc_b, out);
}